// Round 2
// baseline (2128.651 us; speedup 1.0000x reference)
//
#include <hip/hip_runtime.h>
#include <hip/hip_fp16.h>

#define NN 200000   // nodes
#define NE 600000   // edges
#define NG 8192     // graphs
#define DIM 128
#define AV 119      // atom vocab
#define BV 5        // bond vocab

typedef __half half_t;

__device__ inline uint2 pack4h(float a, float b, float c, float d) {
  union { uint2 u; __half2 h[2]; } r;
  r.h[0] = __floats2half2_rn(a, b);
  r.h[1] = __floats2half2_rn(c, d);
  return r.u;
}

// ---------------- init: deg=1, pooled=0, cnt=0 ----------------
__global__ __launch_bounds__(256) void k_init(float* __restrict__ deg,
                                              float* __restrict__ pooled,
                                              float* __restrict__ cnt) {
  int i = blockIdx.x * 256 + threadIdx.x;
  if (i < NN) deg[i] = 1.0f;
  if (i < NG * DIM) pooled[i] = 0.0f;
  if (i < NG) cnt[i] = 0.0f;
}

// ---------------- degree over row (=edge_index[0]) ----------------
__global__ __launch_bounds__(256) void k_deg(const int* __restrict__ ei,
                                             float* __restrict__ deg) {
  int e = blockIdx.x * 256 + threadIdx.x;
  if (e < NE) unsafeAtomicAdd(&deg[ei[e]], 1.0f);
}

__global__ __launch_bounds__(256) void k_dinv(const float* __restrict__ deg,
                                              float* __restrict__ dinv,
                                              float* __restrict__ invdeg) {
  int n = blockIdx.x * 256 + threadIdx.x;
  if (n < NN) {
    float d = deg[n];
    dinv[n] = 1.0f / sqrtf(d);
    invdeg[n] = 1.0f / d;
  }
}

// ---------------- AtomEncoder: AGG[n][d] = sum_c atom_emb[c][x[n,c]][d] (fp16 out) ----------------
__global__ __launch_bounds__(256) void k_atom(const int* __restrict__ xf,
                                              const float* __restrict__ aemb,
                                              half_t* __restrict__ A) {
  int n = blockIdx.x * 4 + (threadIdx.x >> 6);
  int d = (threadIdx.x & 63) * 2;
  if (n >= NN) return;
  float sx = 0.f, sy = 0.f;
#pragma unroll
  for (int c = 0; c < 9; ++c) {
    int idx = xf[n * 9 + c];
    float2 v = *(const float2*)(aemb + (size_t)(c * AV + idx) * DIM + d);
    sx += v.x; sy += v.y;
  }
  *(__half2*)(A + (size_t)n * DIM + d) = __floats2half2_rn(sx, sy);
}

// ---------------- fused layer GEMM ----------------
// HB = act(AGG) @ W + bias   (act = BN+ReLU of prev layer if ACT)
// AGG = relu(HB + root) * invdeg   (self-term seed, in-place; block-local rows only)
template <int ACT>
__global__ __launch_bounds__(256) void k_gemm(
    const half_t* __restrict__ Ain, const float* __restrict__ W,
    const float* __restrict__ bias, const float* __restrict__ root,
    const float* __restrict__ invdeg, const float* __restrict__ gamma,
    const float* __restrict__ beta, half_t* __restrict__ HB,
    half_t* __restrict__ Aout) {
  __shared__ __align__(16) float As[DIM][DIM];  // transposed: As[k][r]
  __shared__ __align__(16) float Wl[DIM][DIM];  // Wl[k][c]
  const int tid = threadIdx.x;
  const int bm = blockIdx.x * DIM;

#pragma unroll
  for (int it = 0; it < 16; ++it) {
    int idx = it * 256 + tid;
    ((float4*)&Wl[0][0])[idx] = ((const float4*)W)[idx];
  }
  {
    const int sr = tid >> 1;
    const int sc0 = (tid & 1) * 64;
    const int gr = bm + sr;
    const bool valid = gr < NN;
    const float bns = rsqrtf(1.0f + 1e-5f);
    const half_t* ap = Ain + (size_t)gr * DIM;
#pragma unroll
    for (int j = 0; j < 8; ++j) {
      int c = sc0 + j * 8;
      float v[8];
      if (valid) {
        union { uint4 u; __half2 h[4]; } uu;
        uu.u = *(const uint4*)(ap + c);
#pragma unroll
        for (int q = 0; q < 4; ++q) {
          float2 f = __half22float2(uu.h[q]);
          v[2 * q] = f.x; v[2 * q + 1] = f.y;
        }
      } else {
#pragma unroll
        for (int q = 0; q < 8; ++q) v[q] = 0.f;
      }
      if (ACT) {
#pragma unroll
        for (int q = 0; q < 8; ++q)
          v[q] = fmaxf(fmaf(v[q], gamma[c + q] * bns, beta[c + q]), 0.f);
      }
#pragma unroll
      for (int q = 0; q < 8; ++q) As[c + q][sr] = v[q];
    }
  }
  __syncthreads();

  const int tr = tid >> 4;  // 16 row groups of 8
  const int tc = tid & 15;  // 16 col groups: cols tc*4..+4 and 64+tc*4..+4
  float acc[8][8];
#pragma unroll
  for (int i = 0; i < 8; ++i)
#pragma unroll
    for (int j = 0; j < 8; ++j) acc[i][j] = 0.f;

#pragma unroll 4
  for (int k = 0; k < DIM; ++k) {
    float a[8], w[8];
    *(float4*)&a[0] = *(const float4*)&As[k][tr * 8];
    *(float4*)&a[4] = *(const float4*)&As[k][tr * 8 + 4];
    *(float4*)&w[0] = *(const float4*)&Wl[k][tc * 4];
    *(float4*)&w[4] = *(const float4*)&Wl[k][64 + tc * 4];
#pragma unroll
    for (int i = 0; i < 8; ++i)
#pragma unroll
      for (int j = 0; j < 8; ++j) acc[i][j] = fmaf(a[i], w[j], acc[i][j]);
  }

  float4 b0 = *(const float4*)(bias + tc * 4);
  float4 b1 = *(const float4*)(bias + 64 + tc * 4);
  float4 r0 = *(const float4*)(root + tc * 4);
  float4 r1 = *(const float4*)(root + 64 + tc * 4);
#pragma unroll
  for (int i = 0; i < 8; ++i) {
    int r = bm + tr * 8 + i;
    if (r >= NN) break;
    float id = invdeg[r];
    float o[8];
    o[0] = acc[i][0] + b0.x; o[1] = acc[i][1] + b0.y;
    o[2] = acc[i][2] + b0.z; o[3] = acc[i][3] + b0.w;
    o[4] = acc[i][4] + b1.x; o[5] = acc[i][5] + b1.y;
    o[6] = acc[i][6] + b1.z; o[7] = acc[i][7] + b1.w;
    *(uint2*)(HB + (size_t)r * DIM + tc * 4) = pack4h(o[0], o[1], o[2], o[3]);
    *(uint2*)(HB + (size_t)r * DIM + 64 + tc * 4) = pack4h(o[4], o[5], o[6], o[7]);
    float p[8];
    p[0] = fmaxf(o[0] + r0.x, 0.f) * id; p[1] = fmaxf(o[1] + r0.y, 0.f) * id;
    p[2] = fmaxf(o[2] + r0.z, 0.f) * id; p[3] = fmaxf(o[3] + r0.w, 0.f) * id;
    p[4] = fmaxf(o[4] + r1.x, 0.f) * id; p[5] = fmaxf(o[5] + r1.y, 0.f) * id;
    p[6] = fmaxf(o[6] + r1.z, 0.f) * id; p[7] = fmaxf(o[7] + r1.w, 0.f) * id;
    *(uint2*)(Aout + (size_t)r * DIM + tc * 4) = pack4h(p[0], p[1], p[2], p[3]);
    *(uint2*)(Aout + (size_t)r * DIM + 64 + tc * 4) = pack4h(p[4], p[5], p[6], p[7]);
  }
}

// ---------------- edge kernel: AGG[col] += dinv[row]*dinv[col]*relu(HB[row]+ee) ----------------
// 32 lanes per edge (4 dims per lane), 8 groups/block, 8 edges per group.
__global__ __launch_bounds__(256) void k_edge(
    const int* __restrict__ ei, const int* __restrict__ ea,
    const float* __restrict__ bond, const float* __restrict__ dinv,
    const half_t* __restrict__ HB, half_t* __restrict__ AGG) {
  __shared__ __align__(16) float bl[3 * BV * DIM];
  for (int i = threadIdx.x; i < 3 * BV * DIM; i += 256) bl[i] = bond[i];
  __syncthreads();
  const int g = threadIdx.x >> 5;
  const int lane = threadIdx.x & 31;
  const int d = lane * 4;
  const int e0 = blockIdx.x * 64 + g * 8;
#pragma unroll
  for (int t = 0; t < 8; ++t) {
    int e = e0 + t;
    int row = ei[e];
    int col = ei[NE + e];
    float norm = dinv[row] * dinv[col];
    int a0 = ea[e * 3 + 0], a1 = ea[e * 3 + 1], a2 = ea[e * 3 + 2];
    union { uint2 u; __half2 h[2]; } uu;
    uu.u = *(const uint2*)(HB + (size_t)row * DIM + d);
    float2 hlo = __half22float2(uu.h[0]);
    float2 hhi = __half22float2(uu.h[1]);
    float4 e0v = *(const float4*)&bl[(0 * BV + a0) * DIM + d];
    float4 e1v = *(const float4*)&bl[(1 * BV + a1) * DIM + d];
    float4 e2v = *(const float4*)&bl[(2 * BV + a2) * DIM + d];
    float m0 = fmaxf(hlo.x + e0v.x + e1v.x + e2v.x, 0.f) * norm;
    float m1 = fmaxf(hlo.y + e0v.y + e1v.y + e2v.y, 0.f) * norm;
    float m2 = fmaxf(hhi.x + e0v.z + e1v.z + e2v.z, 0.f) * norm;
    float m3 = fmaxf(hhi.y + e0v.w + e1v.w + e2v.w, 0.f) * norm;
    __half2* dst = (__half2*)(AGG + (size_t)col * DIM + d);
    unsafeAtomicAdd(dst + 0, __floats2half2_rn(m0, m1));
    unsafeAtomicAdd(dst + 1, __floats2half2_rn(m2, m3));
  }
}

// ---------------- pooling: run-length accumulate over sorted batch ----------------
__global__ __launch_bounds__(128) void k_pool(const half_t* __restrict__ A,
                                              const int* __restrict__ batch,
                                              float* __restrict__ pooled,
                                              float* __restrict__ cnt) {
  const int d = threadIdx.x;
  const int base = blockIdx.x * 16;
  int curb = batch[base];
  float acc = 0.f, cacc = 0.f;
#pragma unroll
  for (int i = 0; i < 16; ++i) {
    int n = base + i;
    int b = batch[n];
    if (b != curb) {
      unsafeAtomicAdd(&pooled[(size_t)curb * DIM + d], acc);
      if (d == 0) unsafeAtomicAdd(&cnt[curb], cacc);
      curb = b; acc = 0.f; cacc = 0.f;
    }
    acc += __half2float(A[(size_t)n * DIM + d]);
    cacc += 1.f;
  }
  unsafeAtomicAdd(&pooled[(size_t)curb * DIM + d], acc);
  if (d == 0) unsafeAtomicAdd(&cnt[curb], cacc);
}

// ---------------- output GEMM: out = (sums @ out_W) / max(cnt,1) + out_b ----------------
__global__ __launch_bounds__(256) void k_outgemm(const float* __restrict__ P,
                                                 const float* __restrict__ W,
                                                 const float* __restrict__ ob,
                                                 const float* __restrict__ cnt,
                                                 float* __restrict__ out) {
  __shared__ __align__(16) float As[DIM][DIM];
  __shared__ __align__(16) float Wl[DIM][DIM];
  const int tid = threadIdx.x;
  const int bm = blockIdx.x * DIM;
#pragma unroll
  for (int it = 0; it < 16; ++it) {
    int idx = it * 256 + tid;
    ((float4*)&Wl[0][0])[idx] = ((const float4*)W)[idx];
  }
  {
    const int sr = tid >> 1;
    const int sc0 = (tid & 1) * 64;
    const int gr = bm + sr;
#pragma unroll
    for (int j = 0; j < 16; ++j) {
      int c = sc0 + j * 4;
      float4 v = *(const float4*)(P + (size_t)gr * DIM + c);
      As[c + 0][sr] = v.x;
      As[c + 1][sr] = v.y;
      As[c + 2][sr] = v.z;
      As[c + 3][sr] = v.w;
    }
  }
  __syncthreads();
  const int tr = tid >> 4;
  const int tc = tid & 15;
  float acc[8][8];
#pragma unroll
  for (int i = 0; i < 8; ++i)
#pragma unroll
    for (int j = 0; j < 8; ++j) acc[i][j] = 0.f;
#pragma unroll 4
  for (int k = 0; k < DIM; ++k) {
    float a[8], w[8];
    *(float4*)&a[0] = *(const float4*)&As[k][tr * 8];
    *(float4*)&a[4] = *(const float4*)&As[k][tr * 8 + 4];
    *(float4*)&w[0] = *(const float4*)&Wl[k][tc * 4];
    *(float4*)&w[4] = *(const float4*)&Wl[k][64 + tc * 4];
#pragma unroll
    for (int i = 0; i < 8; ++i)
#pragma unroll
      for (int j = 0; j < 8; ++j) acc[i][j] = fmaf(a[i], w[j], acc[i][j]);
  }
  float4 b0 = *(const float4*)(ob + tc * 4);
  float4 b1 = *(const float4*)(ob + 64 + tc * 4);
#pragma unroll
  for (int i = 0; i < 8; ++i) {
    int r = bm + tr * 8 + i;  // 8192 rows exact
    float ic = 1.0f / fmaxf(cnt[r], 1.0f);
    float4 o0, o1;
    o0.x = acc[i][0] * ic + b0.x; o0.y = acc[i][1] * ic + b0.y;
    o0.z = acc[i][2] * ic + b0.z; o0.w = acc[i][3] * ic + b0.w;
    o1.x = acc[i][4] * ic + b1.x; o1.y = acc[i][5] * ic + b1.y;
    o1.z = acc[i][6] * ic + b1.z; o1.w = acc[i][7] * ic + b1.w;
    *(float4*)(out + (size_t)r * DIM + tc * 4) = o0;
    *(float4*)(out + (size_t)r * DIM + 64 + tc * 4) = o1;
  }
}

extern "C" void kernel_launch(void* const* d_in, const int* in_sizes, int n_in,
                              void* d_out, int out_size, void* d_ws, size_t ws_size,
                              hipStream_t stream) {
  const int* xf = (const int*)d_in[0];
  const int* ei = (const int*)d_in[1];
  const int* ea = (const int*)d_in[2];
  const int* batch = (const int*)d_in[3];
  const float* aemb = (const float*)d_in[4];
  const float* bemb = (const float*)d_in[5];
  const float* Wsp = (const float*)d_in[6];
  const float* bsp = (const float*)d_in[7];
  const float* roots = (const float*)d_in[8];
  const float* gamma = (const float*)d_in[9];
  const float* beta = (const float*)d_in[10];
  const float* oW = (const float*)d_in[11];
  const float* ob = (const float*)d_in[12];
  float* out = (float*)d_out;

  // workspace layout (109.0 MB total):
  half_t* AGG = (half_t*)d_ws;                   // [NN*DIM] fp16  (51.2 MB)
  half_t* HB = AGG + (size_t)NN * DIM;           // [NN*DIM] fp16  (51.2 MB)
  float* deg = (float*)(HB + (size_t)NN * DIM);  // [NN]
  float* dinv = deg + NN;                        // [NN]
  float* invdeg = dinv + NN;                     // [NN]
  float* pooled = invdeg + NN;                   // [NG*DIM]
  float* cnt = pooled + (size_t)NG * DIM;        // [NG]

  k_init<<<(NG * DIM + 255) / 256, 256, 0, stream>>>(deg, pooled, cnt);
  k_deg<<<(NE + 255) / 256, 256, 0, stream>>>(ei, deg);
  k_dinv<<<(NN + 255) / 256, 256, 0, stream>>>(deg, dinv, invdeg);
  k_atom<<<NN / 4, 256, 0, stream>>>(xf, aemb, AGG);

  const int gblocks = (NN + DIM - 1) / DIM;  // 1563
  for (int i = 0; i < 5; ++i) {
    const float* W = Wsp + (size_t)i * DIM * DIM;
    const float* bias = bsp + (size_t)i * DIM;
    const float* root = roots + (size_t)i * DIM;
    if (i == 0)
      k_gemm<0><<<gblocks, 256, 0, stream>>>(AGG, W, bias, root, invdeg,
                                             nullptr, nullptr, HB, AGG);
    else
      k_gemm<1><<<gblocks, 256, 0, stream>>>(AGG, W, bias, root, invdeg,
                                             gamma + (size_t)(i - 1) * DIM,
                                             beta + (size_t)(i - 1) * DIM, HB, AGG);
    k_edge<<<NE / 64, 256, 0, stream>>>(ei, ea, bemb + (size_t)i * 3 * BV * DIM,
                                        dinv, HB, AGG);
  }
  k_pool<<<NN / 16, 128, 0, stream>>>(AGG, batch, pooled, cnt);
  k_outgemm<<<NG / DIM, 256, 0, stream>>>(pooled, oW, ob, cnt, out);
}

// Round 3
// 1602.121 us; speedup vs baseline: 1.3286x; 1.3286x over previous
//
#include <hip/hip_runtime.h>
#include <hip/hip_fp16.h>

#define NN 200000   // nodes
#define NE 600000   // edges
#define NG 8192     // graphs
#define DIM 128
#define AV 119      // atom vocab
#define BV 5        // bond vocab

typedef __half half_t;

__device__ inline uint2 pack4h(float a, float b, float c, float d) {
  union { uint2 u; __half2 h[2]; } r;
  r.h[0] = __floats2half2_rn(a, b);
  r.h[1] = __floats2half2_rn(c, d);
  return r.u;
}

// ---------------- init: deg=1, indeg=0 ----------------
__global__ __launch_bounds__(256) void k_init(float* __restrict__ deg,
                                              int* __restrict__ indeg) {
  int i = blockIdx.x * 256 + threadIdx.x;
  if (i < NN) { deg[i] = 1.0f; indeg[i] = 0; }
}

// ---------------- degree (over row) + in-degree (over col) ----------------
__global__ __launch_bounds__(256) void k_deg(const int* __restrict__ ei,
                                             float* __restrict__ deg,
                                             int* __restrict__ indeg) {
  int e = blockIdx.x * 256 + threadIdx.x;
  if (e < NE) {
    unsafeAtomicAdd(&deg[ei[e]], 1.0f);
    atomicAdd(&indeg[ei[NE + e]], 1);
  }
}

__global__ __launch_bounds__(256) void k_dinv(const float* __restrict__ deg,
                                              float* __restrict__ dinv,
                                              float* __restrict__ invdeg) {
  int n = blockIdx.x * 256 + threadIdx.x;
  if (n < NN) {
    float d = deg[n];
    dinv[n] = 1.0f / sqrtf(d);
    invdeg[n] = 1.0f / d;
  }
}

// ---------------- exclusive scan of indeg -> writecur (single block) ----------------
__global__ __launch_bounds__(1024) void k_scan(const int* __restrict__ indeg,
                                               int* __restrict__ writecur) {
  __shared__ int s[1024];
  const int t = threadIdx.x;
  const int R = (NN + 1023) / 1024;  // 196
  const int lo = t * R, hi = min(lo + R, NN);
  int sum = 0;
  for (int i = lo; i < hi; ++i) sum += indeg[i];
  s[t] = sum;
  __syncthreads();
  for (int off = 1; off < 1024; off <<= 1) {
    int v = (t >= off) ? s[t - off] : 0;
    __syncthreads();
    s[t] += v;
    __syncthreads();
  }
  int run = s[t] - sum;  // exclusive prefix of this thread's range
  for (int i = lo; i < hi; ++i) {
    writecur[i] = run;
    run += indeg[i];
  }
}

// ---------------- fill CSR: epk[pos] = row | a0<<18 | a1<<21 | a2<<24 ----------------
// after this kernel, writecur[n] == end offset of node n's edge list.
__global__ __launch_bounds__(256) void k_fill(const int* __restrict__ ei,
                                              const int* __restrict__ ea,
                                              int* __restrict__ writecur,
                                              int* __restrict__ epk) {
  int e = blockIdx.x * 256 + threadIdx.x;
  if (e >= NE) return;
  int row = ei[e];
  int col = ei[NE + e];
  int pos = atomicAdd(&writecur[col], 1);
  epk[pos] = row | (ea[e * 3] << 18) | (ea[e * 3 + 1] << 21) | (ea[e * 3 + 2] << 24);
}

// ---------------- AtomEncoder: AGG[n][d] = sum_c atom_emb[c][x[n,c]][d] ----------------
__global__ __launch_bounds__(256) void k_atom(const int* __restrict__ xf,
                                              const float* __restrict__ aemb,
                                              half_t* __restrict__ A) {
  int n = blockIdx.x * 4 + (threadIdx.x >> 6);
  int d = (threadIdx.x & 63) * 2;
  float sx = 0.f, sy = 0.f;
#pragma unroll
  for (int c = 0; c < 9; ++c) {
    int idx = xf[n * 9 + c];
    float2 v = *(const float2*)(aemb + (size_t)(c * AV + idx) * DIM + d);
    sx += v.x; sy += v.y;
  }
  *(__half2*)(A + (size_t)n * DIM + d) = __floats2half2_rn(sx, sy);
}

// ---------------- layer GEMM: HB = act(AGG) @ W + bias ----------------
// act = BN(prev layer)+ReLU if ACT else identity. 128x128 tile, 8x8 micro-tile.
template <int ACT>
__global__ __launch_bounds__(256) void k_gemm(
    const half_t* __restrict__ Ain, const float* __restrict__ W,
    const float* __restrict__ bias, const float* __restrict__ gamma,
    const float* __restrict__ beta, half_t* __restrict__ HB) {
  __shared__ __align__(16) float As[DIM][DIM];  // transposed: As[k][r]
  __shared__ __align__(16) float Wl[DIM][DIM];  // Wl[k][c]
  const int tid = threadIdx.x;
  const int bm = blockIdx.x * DIM;

#pragma unroll
  for (int it = 0; it < 16; ++it) {
    int idx = it * 256 + tid;
    ((float4*)&Wl[0][0])[idx] = ((const float4*)W)[idx];
  }
  {
    const int sr = tid >> 1;
    const int sc0 = (tid & 1) * 64;
    const int gr = bm + sr;
    const bool valid = gr < NN;
    const float bns = rsqrtf(1.0f + 1e-5f);
    const half_t* ap = Ain + (size_t)gr * DIM;
#pragma unroll
    for (int j = 0; j < 8; ++j) {
      int c = sc0 + j * 8;
      float v[8];
      if (valid) {
        union { uint4 u; __half2 h[4]; } uu;
        uu.u = *(const uint4*)(ap + c);
#pragma unroll
        for (int q = 0; q < 4; ++q) {
          float2 f = __half22float2(uu.h[q]);
          v[2 * q] = f.x; v[2 * q + 1] = f.y;
        }
      } else {
#pragma unroll
        for (int q = 0; q < 8; ++q) v[q] = 0.f;
      }
      if (ACT) {
#pragma unroll
        for (int q = 0; q < 8; ++q)
          v[q] = fmaxf(fmaf(v[q], gamma[c + q] * bns, beta[c + q]), 0.f);
      }
#pragma unroll
      for (int q = 0; q < 8; ++q) As[c + q][sr] = v[q];
    }
  }
  __syncthreads();

  const int tr = tid >> 4;
  const int tc = tid & 15;
  float acc[8][8];
#pragma unroll
  for (int i = 0; i < 8; ++i)
#pragma unroll
    for (int j = 0; j < 8; ++j) acc[i][j] = 0.f;

#pragma unroll 4
  for (int k = 0; k < DIM; ++k) {
    float a[8], w[8];
    *(float4*)&a[0] = *(const float4*)&As[k][tr * 8];
    *(float4*)&a[4] = *(const float4*)&As[k][tr * 8 + 4];
    *(float4*)&w[0] = *(const float4*)&Wl[k][tc * 4];
    *(float4*)&w[4] = *(const float4*)&Wl[k][64 + tc * 4];
#pragma unroll
    for (int i = 0; i < 8; ++i)
#pragma unroll
      for (int j = 0; j < 8; ++j) acc[i][j] = fmaf(a[i], w[j], acc[i][j]);
  }

  float4 b0 = *(const float4*)(bias + tc * 4);
  float4 b1 = *(const float4*)(bias + 64 + tc * 4);
#pragma unroll
  for (int i = 0; i < 8; ++i) {
    int r = bm + tr * 8 + i;
    if (r >= NN) break;
    *(uint2*)(HB + (size_t)r * DIM + tc * 4) =
        pack4h(acc[i][0] + b0.x, acc[i][1] + b0.y, acc[i][2] + b0.z, acc[i][3] + b0.w);
    *(uint2*)(HB + (size_t)r * DIM + 64 + tc * 4) =
        pack4h(acc[i][4] + b1.x, acc[i][5] + b1.y, acc[i][6] + b1.z, acc[i][7] + b1.w);
  }
}

// ---------------- gather: AGG[n] = relu(HB[n]+root)*invdeg[n]
//                  + sum_{e in CSR[n]} dinv[n]*dinv[row]*relu(HB[row]+ee) ----------------
// 32 lanes per node (4 dims/lane), 8 nodes per 256-block. fp32 accumulation, no atomics.
__global__ __launch_bounds__(256) void k_gather(
    const int* __restrict__ indeg, const int* __restrict__ wend,
    const int* __restrict__ epk, const float* __restrict__ bond,
    const float* __restrict__ dinv, const float* __restrict__ invdeg,
    const float* __restrict__ root, const half_t* __restrict__ HB,
    half_t* __restrict__ AGG) {
  __shared__ __align__(16) float bl[3 * BV * DIM];
  for (int i = threadIdx.x; i < 3 * BV * DIM; i += 256) bl[i] = bond[i];
  __syncthreads();
  const int n = blockIdx.x * 8 + (threadIdx.x >> 5);
  const int d = (threadIdx.x & 31) * 4;

  union { uint2 u; __half2 h[2]; } uu;
  uu.u = *(const uint2*)(HB + (size_t)n * DIM + d);
  float2 slo = __half22float2(uu.h[0]);
  float2 shi = __half22float2(uu.h[1]);
  float4 rt = *(const float4*)(root + d);
  const float idg = invdeg[n];
  float a0 = fmaxf(slo.x + rt.x, 0.f) * idg;
  float a1 = fmaxf(slo.y + rt.y, 0.f) * idg;
  float a2 = fmaxf(shi.x + rt.z, 0.f) * idg;
  float a3 = fmaxf(shi.y + rt.w, 0.f) * idg;

  const float dc = dinv[n];
  const int e1 = wend[n];
  const int e0 = e1 - indeg[n];
  for (int j = e0; j < e1; ++j) {
    int pk = epk[j];
    int row = pk & 0x3FFFF;
    float nr = dc * dinv[row];
    uu.u = *(const uint2*)(HB + (size_t)row * DIM + d);
    float2 flo = __half22float2(uu.h[0]);
    float2 fhi = __half22float2(uu.h[1]);
    float4 b0v = *(const float4*)&bl[(((pk >> 18) & 7)) * DIM + d];
    float4 b1v = *(const float4*)&bl[(BV + ((pk >> 21) & 7)) * DIM + d];
    float4 b2v = *(const float4*)&bl[(2 * BV + ((pk >> 24) & 7)) * DIM + d];
    a0 += fmaxf(flo.x + b0v.x + b1v.x + b2v.x, 0.f) * nr;
    a1 += fmaxf(flo.y + b0v.y + b1v.y + b2v.y, 0.f) * nr;
    a2 += fmaxf(fhi.x + b0v.z + b1v.z + b2v.z, 0.f) * nr;
    a3 += fmaxf(fhi.y + b0v.w + b1v.w + b2v.w, 0.f) * nr;
  }
  *(uint2*)(AGG + (size_t)n * DIM + d) = pack4h(a0, a1, a2, a3);
}

// ---------------- pooling: run-length accumulate over sorted batch ----------------
__global__ __launch_bounds__(128) void k_pool(const half_t* __restrict__ A,
                                              const int* __restrict__ batch,
                                              float* __restrict__ pooled,
                                              float* __restrict__ cnt) {
  const int d = threadIdx.x;
  const int base = blockIdx.x * 16;
  int curb = batch[base];
  float acc = 0.f, cacc = 0.f;
#pragma unroll
  for (int i = 0; i < 16; ++i) {
    int n = base + i;
    int b = batch[n];
    if (b != curb) {
      unsafeAtomicAdd(&pooled[(size_t)curb * DIM + d], acc);
      if (d == 0) unsafeAtomicAdd(&cnt[curb], cacc);
      curb = b; acc = 0.f; cacc = 0.f;
    }
    acc += __half2float(A[(size_t)n * DIM + d]);
    cacc += 1.f;
  }
  unsafeAtomicAdd(&pooled[(size_t)curb * DIM + d], acc);
  if (d == 0) unsafeAtomicAdd(&cnt[curb], cacc);
}

// ---------------- output GEMM: out = (sums @ out_W) / max(cnt,1) + out_b ----------------
__global__ __launch_bounds__(256) void k_outgemm(const float* __restrict__ P,
                                                 const float* __restrict__ W,
                                                 const float* __restrict__ ob,
                                                 const float* __restrict__ cnt,
                                                 float* __restrict__ out) {
  __shared__ __align__(16) float As[DIM][DIM];
  __shared__ __align__(16) float Wl[DIM][DIM];
  const int tid = threadIdx.x;
  const int bm = blockIdx.x * DIM;
#pragma unroll
  for (int it = 0; it < 16; ++it) {
    int idx = it * 256 + tid;
    ((float4*)&Wl[0][0])[idx] = ((const float4*)W)[idx];
  }
  {
    const int sr = tid >> 1;
    const int sc0 = (tid & 1) * 64;
    const int gr = bm + sr;
#pragma unroll
    for (int j = 0; j < 16; ++j) {
      int c = sc0 + j * 4;
      float4 v = *(const float4*)(P + (size_t)gr * DIM + c);
      As[c + 0][sr] = v.x;
      As[c + 1][sr] = v.y;
      As[c + 2][sr] = v.z;
      As[c + 3][sr] = v.w;
    }
  }
  __syncthreads();
  const int tr = tid >> 4;
  const int tc = tid & 15;
  float acc[8][8];
#pragma unroll
  for (int i = 0; i < 8; ++i)
#pragma unroll
    for (int j = 0; j < 8; ++j) acc[i][j] = 0.f;
#pragma unroll 4
  for (int k = 0; k < DIM; ++k) {
    float a[8], w[8];
    *(float4*)&a[0] = *(const float4*)&As[k][tr * 8];
    *(float4*)&a[4] = *(const float4*)&As[k][tr * 8 + 4];
    *(float4*)&w[0] = *(const float4*)&Wl[k][tc * 4];
    *(float4*)&w[4] = *(const float4*)&Wl[k][64 + tc * 4];
#pragma unroll
    for (int i = 0; i < 8; ++i)
#pragma unroll
      for (int j = 0; j < 8; ++j) acc[i][j] = fmaf(a[i], w[j], acc[i][j]);
  }
  float4 b0 = *(const float4*)(ob + tc * 4);
  float4 b1 = *(const float4*)(ob + 64 + tc * 4);
#pragma unroll
  for (int i = 0; i < 8; ++i) {
    int r = bm + tr * 8 + i;  // 8192 rows exact
    float ic = 1.0f / fmaxf(cnt[r], 1.0f);
    float4 o0, o1;
    o0.x = acc[i][0] * ic + b0.x; o0.y = acc[i][1] * ic + b0.y;
    o0.z = acc[i][2] * ic + b0.z; o0.w = acc[i][3] * ic + b0.w;
    o1.x = acc[i][4] * ic + b1.x; o1.y = acc[i][5] * ic + b1.y;
    o1.z = acc[i][6] * ic + b1.z; o1.w = acc[i][7] * ic + b1.w;
    *(float4*)(out + (size_t)r * DIM + tc * 4) = o0;
    *(float4*)(out + (size_t)r * DIM + 64 + tc * 4) = o1;
  }
}

extern "C" void kernel_launch(void* const* d_in, const int* in_sizes, int n_in,
                              void* d_out, int out_size, void* d_ws, size_t ws_size,
                              hipStream_t stream) {
  const int* xf = (const int*)d_in[0];
  const int* ei = (const int*)d_in[1];
  const int* ea = (const int*)d_in[2];
  const int* batch = (const int*)d_in[3];
  const float* aemb = (const float*)d_in[4];
  const float* bemb = (const float*)d_in[5];
  const float* Wsp = (const float*)d_in[6];
  const float* bsp = (const float*)d_in[7];
  const float* roots = (const float*)d_in[8];
  const float* gamma = (const float*)d_in[9];
  const float* beta = (const float*)d_in[10];
  const float* oW = (const float*)d_in[11];
  const float* ob = (const float*)d_in[12];
  float* out = (float*)d_out;

  // workspace layout (108.8 MB):
  half_t* AGG = (half_t*)d_ws;                     // [NN*DIM] fp16  51.2 MB
  half_t* HB = AGG + (size_t)NN * DIM;             // [NN*DIM] fp16  51.2 MB
  float* deg = (float*)(HB + (size_t)NN * DIM);    // [NN]
  float* dinv = deg + NN;                          // [NN]
  float* invdeg = dinv + NN;                       // [NN]
  int* indeg = (int*)(invdeg + NN);                // [NN]
  int* writecur = indeg + NN;                      // [NN]
  int* epk = writecur + NN;                        // [NE]
  // pooled/cnt overlay dead HB at pool time (zeroed just before k_pool):
  float* pooled = (float*)HB;                      // [NG*DIM]
  float* cnt = pooled + (size_t)NG * DIM;          // [NG]

  k_init<<<(NN + 255) / 256, 256, 0, stream>>>(deg, indeg);
  k_deg<<<(NE + 255) / 256, 256, 0, stream>>>(ei, deg, indeg);
  k_dinv<<<(NN + 255) / 256, 256, 0, stream>>>(deg, dinv, invdeg);
  k_scan<<<1, 1024, 0, stream>>>(indeg, writecur);
  k_fill<<<(NE + 255) / 256, 256, 0, stream>>>(ei, ea, writecur, epk);
  k_atom<<<NN / 4, 256, 0, stream>>>(xf, aemb, AGG);

  const int gblocks = (NN + DIM - 1) / DIM;  // 1563
  for (int i = 0; i < 5; ++i) {
    const float* W = Wsp + (size_t)i * DIM * DIM;
    const float* bias = bsp + (size_t)i * DIM;
    const float* root = roots + (size_t)i * DIM;
    if (i == 0)
      k_gemm<0><<<gblocks, 256, 0, stream>>>(AGG, W, bias, nullptr, nullptr, HB);
    else
      k_gemm<1><<<gblocks, 256, 0, stream>>>(AGG, W, bias,
                                             gamma + (size_t)(i - 1) * DIM,
                                             beta + (size_t)(i - 1) * DIM, HB);
    k_gather<<<NN / 8, 256, 0, stream>>>(indeg, writecur, epk,
                                         bemb + (size_t)i * 3 * BV * DIM, dinv,
                                         invdeg, root, HB, AGG);
  }
  hipMemsetAsync(pooled, 0, (size_t)(NG * DIM + NG) * sizeof(float), stream);
  k_pool<<<NN / 16, 128, 0, stream>>>(AGG, batch, pooled, cnt);
  k_outgemm<<<NG / DIM, 256, 0, stream>>>(pooled, oW, ob, cnt, out);
}

// Round 7
// 1154.543 us; speedup vs baseline: 1.8437x; 1.3877x over previous
//
#include <hip/hip_runtime.h>
#include <hip/hip_fp16.h>

#define NN 200000   // nodes
#define NE 600000   // edges
#define NG 8192     // graphs
#define DIM 128
#define AV 119      // atom vocab
#define BV 5        // bond vocab
#define NBLK 782    // ceil(NN/256) for scan

typedef __half half_t;
typedef _Float16 f16x8 __attribute__((ext_vector_type(8)));
typedef float f32x4 __attribute__((ext_vector_type(4)));

union AF { uint4 u; __half2 h[4]; f16x8 v; _Float16 f[8]; };

__device__ inline uint2 pack4h(float a, float b, float c, float d) {
  union { uint2 u; __half2 h[2]; } r;
  r.h[0] = __floats2half2_rn(a, b);
  r.h[1] = __floats2half2_rn(c, d);
  return r.u;
}

// ---------------- init ----------------
__global__ __launch_bounds__(256) void k_init(float* __restrict__ deg,
                                              int* __restrict__ indeg) {
  int i = blockIdx.x * 256 + threadIdx.x;
  if (i < NN) { deg[i] = 1.0f; indeg[i] = 0; }
}

// ---------------- degree (over row) + in-degree (over col) ----------------
__global__ __launch_bounds__(256) void k_deg(const int* __restrict__ ei,
                                             float* __restrict__ deg,
                                             int* __restrict__ indeg) {
  int e = blockIdx.x * 256 + threadIdx.x;
  if (e < NE) {
    unsafeAtomicAdd(&deg[ei[e]], 1.0f);
    atomicAdd(&indeg[ei[NE + e]], 1);
  }
}

__global__ __launch_bounds__(256) void k_dinv(const float* __restrict__ deg,
                                              float* __restrict__ dinv,
                                              float* __restrict__ invdeg) {
  int n = blockIdx.x * 256 + threadIdx.x;
  if (n < NN) {
    float d = deg[n];
    dinv[n] = 1.0f / sqrtf(d);
    invdeg[n] = 1.0f / d;
  }
}

// ---------------- 3-phase exclusive scan of indeg -> writecur ----------------
__global__ __launch_bounds__(256) void k_scansum(const int* __restrict__ indeg,
                                                 int* __restrict__ bsum) {
  __shared__ int s[256];
  int i = blockIdx.x * 256 + threadIdx.x;
  int v = (i < NN) ? indeg[i] : 0;
  s[threadIdx.x] = v;
  __syncthreads();
  for (int off = 128; off > 0; off >>= 1) {
    if (threadIdx.x < off) s[threadIdx.x] += s[threadIdx.x + off];
    __syncthreads();
  }
  if (threadIdx.x == 0) bsum[blockIdx.x] = s[0];
}

__global__ __launch_bounds__(1024) void k_scanmid(const int* __restrict__ bsum,
                                                  int* __restrict__ boff) {
  __shared__ int s[1024];
  int t = threadIdx.x;
  int v = (t < NBLK) ? bsum[t] : 0;
  s[t] = v;
  __syncthreads();
  for (int off = 1; off < 1024; off <<= 1) {
    int x = (t >= off) ? s[t - off] : 0;
    __syncthreads();
    s[t] += x;
    __syncthreads();
  }
  if (t < NBLK) boff[t] = s[t] - v;
}

__global__ __launch_bounds__(256) void k_scanfinal(const int* __restrict__ indeg,
                                                   const int* __restrict__ boff,
                                                   int* __restrict__ writecur) {
  __shared__ int s[256];
  int i = blockIdx.x * 256 + threadIdx.x;
  int v = (i < NN) ? indeg[i] : 0;
  s[threadIdx.x] = v;
  __syncthreads();
  for (int off = 1; off < 256; off <<= 1) {
    int x = (threadIdx.x >= off) ? s[threadIdx.x - off] : 0;
    __syncthreads();
    s[threadIdx.x] += x;
    __syncthreads();
  }
  if (i < NN) writecur[i] = s[threadIdx.x] - v + boff[blockIdx.x];
}

// ---------------- fill CSR: epk[pos] = row | a0<<18 | a1<<21 | a2<<24 ----------------
__global__ __launch_bounds__(256) void k_fill(const int* __restrict__ ei,
                                              const int* __restrict__ ea,
                                              int* __restrict__ writecur,
                                              int* __restrict__ epk) {
  int e = blockIdx.x * 256 + threadIdx.x;
  if (e >= NE) return;
  int row = ei[e];
  int col = ei[NE + e];
  int pos = atomicAdd(&writecur[col], 1);
  epk[pos] = row | (ea[e * 3] << 18) | (ea[e * 3 + 1] << 21) | (ea[e * 3 + 2] << 24);
}

// ---------------- AtomEncoder ----------------
__global__ __launch_bounds__(256) void k_atom(const int* __restrict__ xf,
                                              const float* __restrict__ aemb,
                                              half_t* __restrict__ A) {
  int n = blockIdx.x * 4 + (threadIdx.x >> 6);
  int d = (threadIdx.x & 63) * 2;
  float sx = 0.f, sy = 0.f;
#pragma unroll
  for (int c = 0; c < 9; ++c) {
    int idx = xf[n * 9 + c];
    float2 v = *(const float2*)(aemb + (size_t)(c * AV + idx) * DIM + d);
    sx += v.x; sy += v.y;
  }
  *(__half2*)(A + (size_t)n * DIM + d) = __floats2half2_rn(sx, sy);
}

// ---------------- MFMA layer GEMM: HB = act(AGG) @ W + bias ----------------
// 4 waves/block; wave covers 128 rows x 32 cols. W in registers as hi/lo fp16
// pair (fp32-accurate). A loaded direct from global fp16, activated in-register.
template <int ACT>
__global__ __launch_bounds__(256) void k_gemm(
    const half_t* __restrict__ Ain, const float* __restrict__ W,
    const float* __restrict__ bias, const float* __restrict__ gamma,
    const float* __restrict__ beta, half_t* __restrict__ HB) {
  const int tid = threadIdx.x;
  const int lane = tid & 63;
  const int wave = tid >> 6;
  const int bm = blockIdx.x * DIM;
  const int lr = lane & 15;   // M/N index within 16x16 tile
  const int kg = lane >> 4;   // k-group 0..3
  const int n0 = wave * 32;

  // W fragments (hi/lo split): wf[nt][ks]
  f16x8 wh[2][4], wl[2][4];
#pragma unroll
  for (int nt = 0; nt < 2; ++nt) {
    const int col = n0 + nt * 16 + lr;
#pragma unroll
    for (int ks = 0; ks < 4; ++ks) {
      const int kb = ks * 32 + kg * 8;
      AF h_, l_;
#pragma unroll
      for (int j = 0; j < 8; ++j) {
        float w = W[(kb + j) * DIM + col];
        _Float16 hi = (_Float16)w;
        h_.f[j] = hi;
        l_.f[j] = (_Float16)(w - (float)hi);
      }
      wh[nt][ks] = h_.v;
      wl[nt][ks] = l_.v;
    }
  }

  f32x4 acc[8][2];
#pragma unroll
  for (int mt = 0; mt < 8; ++mt)
#pragma unroll
    for (int nt = 0; nt < 2; ++nt) acc[mt][nt] = (f32x4){0.f, 0.f, 0.f, 0.f};

  const float bns = rsqrtf(1.0f + 1e-5f);
#pragma unroll
  for (int ks = 0; ks < 4; ++ks) {
    const int kb = ks * 32 + kg * 8;
    float4 g0, g1, e0, e1;
    if (ACT) {
      g0 = *(const float4*)(gamma + kb);
      g1 = *(const float4*)(gamma + kb + 4);
      e0 = *(const float4*)(beta + kb);
      e1 = *(const float4*)(beta + kb + 4);
      g0.x *= bns; g0.y *= bns; g0.z *= bns; g0.w *= bns;
      g1.x *= bns; g1.y *= bns; g1.z *= bns; g1.w *= bns;
    }
    f16x8 af[8];
#pragma unroll
    for (int mt = 0; mt < 8; ++mt) {
      const int row = bm + mt * 16 + lr;
      AF a;
      if (row < NN)
        a.u = *(const uint4*)(Ain + (size_t)row * DIM + kb);
      else
        a.u = make_uint4(0u, 0u, 0u, 0u);
      if (ACT) {
        float2 f0 = __half22float2(a.h[0]);
        float2 f1 = __half22float2(a.h[1]);
        float2 f2 = __half22float2(a.h[2]);
        float2 f3 = __half22float2(a.h[3]);
        f0.x = fmaxf(fmaf(f0.x, g0.x, e0.x), 0.f);
        f0.y = fmaxf(fmaf(f0.y, g0.y, e0.y), 0.f);
        f1.x = fmaxf(fmaf(f1.x, g0.z, e0.z), 0.f);
        f1.y = fmaxf(fmaf(f1.y, g0.w, e0.w), 0.f);
        f2.x = fmaxf(fmaf(f2.x, g1.x, e1.x), 0.f);
        f2.y = fmaxf(fmaf(f2.y, g1.y, e1.y), 0.f);
        f3.x = fmaxf(fmaf(f3.x, g1.z, e1.z), 0.f);
        f3.y = fmaxf(fmaf(f3.y, g1.w, e1.w), 0.f);
        a.h[0] = __floats2half2_rn(f0.x, f0.y);
        a.h[1] = __floats2half2_rn(f1.x, f1.y);
        a.h[2] = __floats2half2_rn(f2.x, f2.y);
        a.h[3] = __floats2half2_rn(f3.x, f3.y);
      }
      af[mt] = a.v;
    }
#pragma unroll
    for (int mt = 0; mt < 8; ++mt)
#pragma unroll
      for (int nt = 0; nt < 2; ++nt) {
        acc[mt][nt] = __builtin_amdgcn_mfma_f32_16x16x32_f16(
            af[mt], wh[nt][ks], acc[mt][nt], 0, 0, 0);
        acc[mt][nt] = __builtin_amdgcn_mfma_f32_16x16x32_f16(
            af[mt], wl[nt][ks], acc[mt][nt], 0, 0, 0);
      }
  }

  // epilogue: D row = (lane>>4)*4 + r (node), col = lane&15 (feature)
#pragma unroll
  for (int nt = 0; nt < 2; ++nt) {
    const int col = n0 + nt * 16 + lr;
    const float bv = bias[col];
#pragma unroll
    for (int mt = 0; mt < 8; ++mt) {
#pragma unroll
      for (int r = 0; r < 4; ++r) {
        const int row = bm + mt * 16 + kg * 4 + r;
        if (row < NN)
          HB[(size_t)row * DIM + col] = __float2half(acc[mt][nt][r] + bv);
      }
    }
  }
}

// ---------------- gather: AGG[n] = relu(HB[n]+root)*invdeg[n] + sum_e ... ----------------
__global__ __launch_bounds__(256) void k_gather(
    const int* __restrict__ indeg, const int* __restrict__ wend,
    const int* __restrict__ epk, const float* __restrict__ bond,
    const float* __restrict__ dinv, const float* __restrict__ invdeg,
    const float* __restrict__ root, const half_t* __restrict__ HB,
    half_t* __restrict__ AGG) {
  __shared__ __align__(16) float bl[3 * BV * DIM];
  for (int i = threadIdx.x; i < 3 * BV * DIM; i += 256) bl[i] = bond[i];
  __syncthreads();
  const int n = blockIdx.x * 8 + (threadIdx.x >> 5);
  const int d = (threadIdx.x & 31) * 4;

  union { uint2 u; __half2 h[2]; } uu;
  uu.u = *(const uint2*)(HB + (size_t)n * DIM + d);
  float2 slo = __half22float2(uu.h[0]);
  float2 shi = __half22float2(uu.h[1]);
  float4 rt = *(const float4*)(root + d);
  const float idg = invdeg[n];
  float a0 = fmaxf(slo.x + rt.x, 0.f) * idg;
  float a1 = fmaxf(slo.y + rt.y, 0.f) * idg;
  float a2 = fmaxf(shi.x + rt.z, 0.f) * idg;
  float a3 = fmaxf(shi.y + rt.w, 0.f) * idg;

  const float dc = dinv[n];
  const int e1 = wend[n];
  const int e0 = e1 - indeg[n];
  for (int j = e0; j < e1; ++j) {
    int pk = epk[j];
    int row = pk & 0x3FFFF;
    float nr = dc * dinv[row];
    uu.u = *(const uint2*)(HB + (size_t)row * DIM + d);
    float2 flo = __half22float2(uu.h[0]);
    float2 fhi = __half22float2(uu.h[1]);
    float4 b0v = *(const float4*)&bl[(((pk >> 18) & 7)) * DIM + d];
    float4 b1v = *(const float4*)&bl[(BV + ((pk >> 21) & 7)) * DIM + d];
    float4 b2v = *(const float4*)&bl[(2 * BV + ((pk >> 24) & 7)) * DIM + d];
    a0 += fmaxf(flo.x + b0v.x + b1v.x + b2v.x, 0.f) * nr;
    a1 += fmaxf(flo.y + b0v.y + b1v.y + b2v.y, 0.f) * nr;
    a2 += fmaxf(fhi.x + b0v.z + b1v.z + b2v.z, 0.f) * nr;
    a3 += fmaxf(fhi.y + b0v.w + b1v.w + b2v.w, 0.f) * nr;
  }
  *(uint2*)(AGG + (size_t)n * DIM + d) = pack4h(a0, a1, a2, a3);
}

// ---------------- pooling ----------------
__global__ __launch_bounds__(128) void k_pool(const half_t* __restrict__ A,
                                              const int* __restrict__ batch,
                                              float* __restrict__ pooled,
                                              float* __restrict__ cnt) {
  const int d = threadIdx.x;
  const int base = blockIdx.x * 16;
  int curb = batch[base];
  float acc = 0.f, cacc = 0.f;
#pragma unroll
  for (int i = 0; i < 16; ++i) {
    int n = base + i;
    int b = batch[n];
    if (b != curb) {
      unsafeAtomicAdd(&pooled[(size_t)curb * DIM + d], acc);
      if (d == 0) unsafeAtomicAdd(&cnt[curb], cacc);
      curb = b; acc = 0.f; cacc = 0.f;
    }
    acc += __half2float(A[(size_t)n * DIM + d]);
    cacc += 1.f;
  }
  unsafeAtomicAdd(&pooled[(size_t)curb * DIM + d], acc);
  if (d == 0) unsafeAtomicAdd(&cnt[curb], cacc);
}

// ---------------- output GEMM ----------------
__global__ __launch_bounds__(256) void k_outgemm(const float* __restrict__ P,
                                                 const float* __restrict__ W,
                                                 const float* __restrict__ ob,
                                                 const float* __restrict__ cnt,
                                                 float* __restrict__ out) {
  __shared__ __align__(16) float As[DIM][DIM];
  __shared__ __align__(16) float Wl[DIM][DIM];
  const int tid = threadIdx.x;
  const int bm = blockIdx.x * DIM;
#pragma unroll
  for (int it = 0; it < 16; ++it) {
    int idx = it * 256 + tid;
    ((float4*)&Wl[0][0])[idx] = ((const float4*)W)[idx];
  }
  {
    const int sr = tid >> 1;
    const int sc0 = (tid & 1) * 64;
    const int gr = bm + sr;
#pragma unroll
    for (int j = 0; j < 16; ++j) {
      int c = sc0 + j * 4;
      float4 v = *(const float4*)(P + (size_t)gr * DIM + c);
      As[c + 0][sr] = v.x;
      As[c + 1][sr] = v.y;
      As[c + 2][sr] = v.z;
      As[c + 3][sr] = v.w;
    }
  }
  __syncthreads();
  const int tr = tid >> 4;
  const int tc = tid & 15;
  float acc[8][8];
#pragma unroll
  for (int i = 0; i < 8; ++i)
#pragma unroll
    for (int j = 0; j < 8; ++j) acc[i][j] = 0.f;
#pragma unroll 4
  for (int k = 0; k < DIM; ++k) {
    float a[8], w[8];
    *(float4*)&a[0] = *(const float4*)&As[k][tr * 8];
    *(float4*)&a[4] = *(const float4*)&As[k][tr * 8 + 4];
    *(float4*)&w[0] = *(const float4*)&Wl[k][tc * 4];
    *(float4*)&w[4] = *(const float4*)&Wl[k][64 + tc * 4];
#pragma unroll
    for (int i = 0; i < 8; ++i)
#pragma unroll
      for (int j = 0; j < 8; ++j) acc[i][j] = fmaf(a[i], w[j], acc[i][j]);
  }
  float4 b0 = *(const float4*)(ob + tc * 4);
  float4 b1 = *(const float4*)(ob + 64 + tc * 4);
#pragma unroll
  for (int i = 0; i < 8; ++i) {
    int r = bm + tr * 8 + i;  // 8192 rows exact
    float ic = 1.0f / fmaxf(cnt[r], 1.0f);
    float4 o0, o1;
    o0.x = acc[i][0] * ic + b0.x; o0.y = acc[i][1] * ic + b0.y;
    o0.z = acc[i][2] * ic + b0.z; o0.w = acc[i][3] * ic + b0.w;
    o1.x = acc[i][4] * ic + b1.x; o1.y = acc[i][5] * ic + b1.y;
    o1.z = acc[i][6] * ic + b1.z; o1.w = acc[i][7] * ic + b1.w;
    *(float4*)(out + (size_t)r * DIM + tc * 4) = o0;
    *(float4*)(out + (size_t)r * DIM + 64 + tc * 4) = o1;
  }
}

extern "C" void kernel_launch(void* const* d_in, const int* in_sizes, int n_in,
                              void* d_out, int out_size, void* d_ws, size_t ws_size,
                              hipStream_t stream) {
  const int* xf = (const int*)d_in[0];
  const int* ei = (const int*)d_in[1];
  const int* ea = (const int*)d_in[2];
  const int* batch = (const int*)d_in[3];
  const float* aemb = (const float*)d_in[4];
  const float* bemb = (const float*)d_in[5];
  const float* Wsp = (const float*)d_in[6];
  const float* bsp = (const float*)d_in[7];
  const float* roots = (const float*)d_in[8];
  const float* gamma = (const float*)d_in[9];
  const float* beta = (const float*)d_in[10];
  const float* oW = (const float*)d_in[11];
  const float* ob = (const float*)d_in[12];
  float* out = (float*)d_out;

  // workspace layout (~108.8 MB):
  half_t* AGG = (half_t*)d_ws;                     // [NN*DIM] fp16
  half_t* HB = AGG + (size_t)NN * DIM;             // [NN*DIM] fp16
  float* deg = (float*)(HB + (size_t)NN * DIM);    // [NN]
  float* dinv = deg + NN;                          // [NN]
  float* invdeg = dinv + NN;                       // [NN]
  int* indeg = (int*)(invdeg + NN);                // [NN]
  int* writecur = indeg + NN;                      // [NN]
  int* epk = writecur + NN;                        // [NE]
  int* bsum = epk + NE;                            // [NBLK]
  int* boff = bsum + NBLK;                         // [NBLK]
  // pooled/cnt overlay dead HB at pool time:
  float* pooled = (float*)HB;                      // [NG*DIM]
  float* cnt = pooled + (size_t)NG * DIM;          // [NG]

  k_init<<<(NN + 255) / 256, 256, 0, stream>>>(deg, indeg);
  k_deg<<<(NE + 255) / 256, 256, 0, stream>>>(ei, deg, indeg);
  k_dinv<<<(NN + 255) / 256, 256, 0, stream>>>(deg, dinv, invdeg);
  k_scansum<<<NBLK, 256, 0, stream>>>(indeg, bsum);
  k_scanmid<<<1, 1024, 0, stream>>>(bsum, boff);
  k_scanfinal<<<NBLK, 256, 0, stream>>>(indeg, boff, writecur);
  k_fill<<<(NE + 255) / 256, 256, 0, stream>>>(ei, ea, writecur, epk);
  k_atom<<<NN / 4, 256, 0, stream>>>(xf, aemb, AGG);

  const int gblocks = (NN + DIM - 1) / DIM;  // 1563
  for (int i = 0; i < 5; ++i) {
    const float* W = Wsp + (size_t)i * DIM * DIM;
    const float* bias = bsp + (size_t)i * DIM;
    const float* root = roots + (size_t)i * DIM;
    if (i == 0)
      k_gemm<0><<<gblocks, 256, 0, stream>>>(AGG, W, bias, nullptr, nullptr, HB);
    else
      k_gemm<1><<<gblocks, 256, 0, stream>>>(AGG, W, bias,
                                             gamma + (size_t)(i - 1) * DIM,
                                             beta + (size_t)(i - 1) * DIM, HB);
    k_gather<<<NN / 8, 256, 0, stream>>>(indeg, writecur, epk,
                                         bemb + (size_t)i * 3 * BV * DIM, dinv,
                                         invdeg, root, HB, AGG);
  }
  hipMemsetAsync(pooled, 0, (size_t)(NG * DIM + NG) * sizeof(float), stream);
  k_pool<<<NN / 16, 128, 0, stream>>>(AGG, batch, pooled, cnt);
  k_outgemm<<<NG / DIM, 256, 0, stream>>>(pooled, oW, ob, cnt, out);
}

// Round 8
// 1027.977 us; speedup vs baseline: 2.0707x; 1.1231x over previous
//
#include <hip/hip_runtime.h>
#include <hip/hip_fp16.h>

#define NN 200000   // nodes
#define NE 600000   // edges
#define NG 8192     // graphs
#define DIM 128
#define AV 119      // atom vocab
#define BV 5        // bond vocab
#define NBLK 782    // ceil(NN/256) for scan

typedef __half half_t;
typedef _Float16 f16x8 __attribute__((ext_vector_type(8)));
typedef float f32x4 __attribute__((ext_vector_type(4)));

union AF { uint4 u; __half2 h[4]; f16x8 v; _Float16 f[8]; };

__device__ inline uint2 pack4h(float a, float b, float c, float d) {
  union { uint2 u; __half2 h[2]; } r;
  r.h[0] = __floats2half2_rn(a, b);
  r.h[1] = __floats2half2_rn(c, d);
  return r.u;
}

// ---------------- init ----------------
__global__ __launch_bounds__(256) void k_init(float* __restrict__ deg,
                                              int* __restrict__ indeg) {
  int i = blockIdx.x * 256 + threadIdx.x;
  if (i < NN) { deg[i] = 1.0f; indeg[i] = 0; }
}

// ---------------- degree (over row) + in-degree (over col) ----------------
__global__ __launch_bounds__(256) void k_deg(const int* __restrict__ ei,
                                             float* __restrict__ deg,
                                             int* __restrict__ indeg) {
  int e = blockIdx.x * 256 + threadIdx.x;
  if (e < NE) {
    unsafeAtomicAdd(&deg[ei[e]], 1.0f);
    atomicAdd(&indeg[ei[NE + e]], 1);
  }
}

__global__ __launch_bounds__(256) void k_dinv(const float* __restrict__ deg,
                                              float* __restrict__ dinv,
                                              float* __restrict__ invdeg) {
  int n = blockIdx.x * 256 + threadIdx.x;
  if (n < NN) {
    float d = deg[n];
    dinv[n] = 1.0f / sqrtf(d);
    invdeg[n] = 1.0f / d;
  }
}

// ---------------- 3-phase exclusive scan of indeg -> writecur ----------------
__global__ __launch_bounds__(256) void k_scansum(const int* __restrict__ indeg,
                                                 int* __restrict__ bsum) {
  __shared__ int s[256];
  int i = blockIdx.x * 256 + threadIdx.x;
  int v = (i < NN) ? indeg[i] : 0;
  s[threadIdx.x] = v;
  __syncthreads();
  for (int off = 128; off > 0; off >>= 1) {
    if (threadIdx.x < off) s[threadIdx.x] += s[threadIdx.x + off];
    __syncthreads();
  }
  if (threadIdx.x == 0) bsum[blockIdx.x] = s[0];
}

__global__ __launch_bounds__(1024) void k_scanmid(const int* __restrict__ bsum,
                                                  int* __restrict__ boff) {
  __shared__ int s[1024];
  int t = threadIdx.x;
  int v = (t < NBLK) ? bsum[t] : 0;
  s[t] = v;
  __syncthreads();
  for (int off = 1; off < 1024; off <<= 1) {
    int x = (t >= off) ? s[t - off] : 0;
    __syncthreads();
    s[t] += x;
    __syncthreads();
  }
  if (t < NBLK) boff[t] = s[t] - v;
}

__global__ __launch_bounds__(256) void k_scanfinal(const int* __restrict__ indeg,
                                                   const int* __restrict__ boff,
                                                   int* __restrict__ writecur) {
  __shared__ int s[256];
  int i = blockIdx.x * 256 + threadIdx.x;
  int v = (i < NN) ? indeg[i] : 0;
  s[threadIdx.x] = v;
  __syncthreads();
  for (int off = 1; off < 256; off <<= 1) {
    int x = (threadIdx.x >= off) ? s[threadIdx.x - off] : 0;
    __syncthreads();
    s[threadIdx.x] += x;
    __syncthreads();
  }
  if (i < NN) writecur[i] = s[threadIdx.x] - v + boff[blockIdx.x];
}

// ---------------- fill CSR: epk[pos] = row | a0<<18 | a1<<21 | a2<<24 ----------------
__global__ __launch_bounds__(256) void k_fill(const int* __restrict__ ei,
                                              const int* __restrict__ ea,
                                              int* __restrict__ writecur,
                                              int* __restrict__ epk) {
  int e = blockIdx.x * 256 + threadIdx.x;
  if (e >= NE) return;
  int row = ei[e];
  int col = ei[NE + e];
  int pos = atomicAdd(&writecur[col], 1);
  epk[pos] = row | (ea[e * 3] << 18) | (ea[e * 3 + 1] << 21) | (ea[e * 3 + 2] << 24);
}

// ---------------- AtomEncoder ----------------
__global__ __launch_bounds__(256) void k_atom(const int* __restrict__ xf,
                                              const float* __restrict__ aemb,
                                              half_t* __restrict__ A) {
  int n = blockIdx.x * 4 + (threadIdx.x >> 6);
  int d = (threadIdx.x & 63) * 2;
  float sx = 0.f, sy = 0.f;
#pragma unroll
  for (int c = 0; c < 9; ++c) {
    int idx = xf[n * 9 + c];
    float2 v = *(const float2*)(aemb + (size_t)(c * AV + idx) * DIM + d);
    sx += v.x; sy += v.y;
  }
  *(__half2*)(A + (size_t)n * DIM + d) = __floats2half2_rn(sx, sy);
}

// ---------------- MFMA layer GEMM: HB = AGG @ W + bias (pure, no activation) ----------------
// 4 waves/block; wave covers 128 rows x 32 cols. W in registers as hi/lo fp16
// pair (fp32-accurate). A feeds MFMA directly from global fp16 — no VALU repack.
__global__ __launch_bounds__(256) void k_gemm(
    const half_t* __restrict__ Ain, const float* __restrict__ W,
    const float* __restrict__ bias, half_t* __restrict__ HB) {
  const int tid = threadIdx.x;
  const int lane = tid & 63;
  const int wave = tid >> 6;
  const int bm = blockIdx.x * DIM;
  const int lr = lane & 15;   // M/N index within 16x16 tile
  const int kg = lane >> 4;   // k-group 0..3
  const int n0 = wave * 32;

  // W fragments (hi/lo split): wf[nt][ks]
  f16x8 wh[2][4], wl[2][4];
#pragma unroll
  for (int nt = 0; nt < 2; ++nt) {
    const int col = n0 + nt * 16 + lr;
#pragma unroll
    for (int ks = 0; ks < 4; ++ks) {
      const int kb = ks * 32 + kg * 8;
      AF h_, l_;
#pragma unroll
      for (int j = 0; j < 8; ++j) {
        float w = W[(kb + j) * DIM + col];
        _Float16 hi = (_Float16)w;
        h_.f[j] = hi;
        l_.f[j] = (_Float16)(w - (float)hi);
      }
      wh[nt][ks] = h_.v;
      wl[nt][ks] = l_.v;
    }
  }

  f32x4 acc[8][2];
#pragma unroll
  for (int mt = 0; mt < 8; ++mt)
#pragma unroll
    for (int nt = 0; nt < 2; ++nt) acc[mt][nt] = (f32x4){0.f, 0.f, 0.f, 0.f};

#pragma unroll
  for (int ks = 0; ks < 4; ++ks) {
    const int kb = ks * 32 + kg * 8;
    AF a[8];
#pragma unroll
    for (int mt = 0; mt < 8; ++mt) {
      const int row = bm + mt * 16 + lr;
      if (row < NN)
        a[mt].u = *(const uint4*)(Ain + (size_t)row * DIM + kb);
      else
        a[mt].u = make_uint4(0u, 0u, 0u, 0u);
    }
#pragma unroll
    for (int mt = 0; mt < 8; ++mt)
#pragma unroll
      for (int nt = 0; nt < 2; ++nt) {
        acc[mt][nt] = __builtin_amdgcn_mfma_f32_16x16x32_f16(
            a[mt].v, wh[nt][ks], acc[mt][nt], 0, 0, 0);
        acc[mt][nt] = __builtin_amdgcn_mfma_f32_16x16x32_f16(
            a[mt].v, wl[nt][ks], acc[mt][nt], 0, 0, 0);
      }
  }

  // epilogue: D row = (lane>>4)*4 + r (node), col = lane&15 (feature)
#pragma unroll
  for (int nt = 0; nt < 2; ++nt) {
    const int col = n0 + nt * 16 + lr;
    const float bv = bias[col];
#pragma unroll
    for (int mt = 0; mt < 8; ++mt) {
#pragma unroll
      for (int r = 0; r < 4; ++r) {
        const int row = bm + mt * 16 + kg * 4 + r;
        if (row < NN)
          HB[(size_t)row * DIM + col] = __float2half(acc[mt][nt][r] + bv);
      }
    }
  }
}

// ---------------- gather: conv output, then (if ACT) BN+ReLU, stored fp16 ----------------
// AGG[n] = act( relu(HB[n]+root)*invdeg[n] + sum_{e in CSR[n]} dinv[n]*dinv[row]*relu(HB[row]+ee) )
template <int ACT>
__global__ __launch_bounds__(256) void k_gather(
    const int* __restrict__ indeg, const int* __restrict__ wend,
    const int* __restrict__ epk, const float* __restrict__ bond,
    const float* __restrict__ dinv, const float* __restrict__ invdeg,
    const float* __restrict__ root, const float* __restrict__ gamma,
    const float* __restrict__ beta, const half_t* __restrict__ HB,
    half_t* __restrict__ AGG) {
  __shared__ __align__(16) float bl[3 * BV * DIM];
  for (int i = threadIdx.x; i < 3 * BV * DIM; i += 256) bl[i] = bond[i];
  __syncthreads();
  const int n = blockIdx.x * 8 + (threadIdx.x >> 5);
  const int d = (threadIdx.x & 31) * 4;

  union { uint2 u; __half2 h[2]; } uu;
  uu.u = *(const uint2*)(HB + (size_t)n * DIM + d);
  float2 slo = __half22float2(uu.h[0]);
  float2 shi = __half22float2(uu.h[1]);
  float4 rt = *(const float4*)(root + d);
  const float idg = invdeg[n];
  float a0 = fmaxf(slo.x + rt.x, 0.f) * idg;
  float a1 = fmaxf(slo.y + rt.y, 0.f) * idg;
  float a2 = fmaxf(shi.x + rt.z, 0.f) * idg;
  float a3 = fmaxf(shi.y + rt.w, 0.f) * idg;

  const float dc = dinv[n];
  const int e1 = wend[n];
  const int e0 = e1 - indeg[n];
  for (int j = e0; j < e1; ++j) {
    int pk = epk[j];
    int row = pk & 0x3FFFF;
    float nr = dc * dinv[row];
    uu.u = *(const uint2*)(HB + (size_t)row * DIM + d);
    float2 flo = __half22float2(uu.h[0]);
    float2 fhi = __half22float2(uu.h[1]);
    float4 b0v = *(const float4*)&bl[(((pk >> 18) & 7)) * DIM + d];
    float4 b1v = *(const float4*)&bl[(BV + ((pk >> 21) & 7)) * DIM + d];
    float4 b2v = *(const float4*)&bl[(2 * BV + ((pk >> 24) & 7)) * DIM + d];
    a0 += fmaxf(flo.x + b0v.x + b1v.x + b2v.x, 0.f) * nr;
    a1 += fmaxf(flo.y + b0v.y + b1v.y + b2v.y, 0.f) * nr;
    a2 += fmaxf(fhi.x + b0v.z + b1v.z + b2v.z, 0.f) * nr;
    a3 += fmaxf(fhi.y + b0v.w + b1v.w + b2v.w, 0.f) * nr;
  }
  if (ACT) {
    const float bns = rsqrtf(1.0f + 1e-5f);
    float4 g = *(const float4*)(gamma + d);
    float4 be = *(const float4*)(beta + d);
    a0 = fmaxf(fmaf(a0, g.x * bns, be.x), 0.f);
    a1 = fmaxf(fmaf(a1, g.y * bns, be.y), 0.f);
    a2 = fmaxf(fmaf(a2, g.z * bns, be.z), 0.f);
    a3 = fmaxf(fmaf(a3, g.w * bns, be.w), 0.f);
  }
  *(uint2*)(AGG + (size_t)n * DIM + d) = pack4h(a0, a1, a2, a3);
}

// ---------------- pooling ----------------
__global__ __launch_bounds__(128) void k_pool(const half_t* __restrict__ A,
                                              const int* __restrict__ batch,
                                              float* __restrict__ pooled,
                                              float* __restrict__ cnt) {
  const int d = threadIdx.x;
  const int base = blockIdx.x * 16;
  int curb = batch[base];
  float acc = 0.f, cacc = 0.f;
#pragma unroll
  for (int i = 0; i < 16; ++i) {
    int n = base + i;
    int b = batch[n];
    if (b != curb) {
      unsafeAtomicAdd(&pooled[(size_t)curb * DIM + d], acc);
      if (d == 0) unsafeAtomicAdd(&cnt[curb], cacc);
      curb = b; acc = 0.f; cacc = 0.f;
    }
    acc += __half2float(A[(size_t)n * DIM + d]);
    cacc += 1.f;
  }
  unsafeAtomicAdd(&pooled[(size_t)curb * DIM + d], acc);
  if (d == 0) unsafeAtomicAdd(&cnt[curb], cacc);
}

// ---------------- output GEMM ----------------
__global__ __launch_bounds__(256) void k_outgemm(const float* __restrict__ P,
                                                 const float* __restrict__ W,
                                                 const float* __restrict__ ob,
                                                 const float* __restrict__ cnt,
                                                 float* __restrict__ out) {
  __shared__ __align__(16) float As[DIM][DIM];
  __shared__ __align__(16) float Wl[DIM][DIM];
  const int tid = threadIdx.x;
  const int bm = blockIdx.x * DIM;
#pragma unroll
  for (int it = 0; it < 16; ++it) {
    int idx = it * 256 + tid;
    ((float4*)&Wl[0][0])[idx] = ((const float4*)W)[idx];
  }
  {
    const int sr = tid >> 1;
    const int sc0 = (tid & 1) * 64;
    const int gr = bm + sr;
#pragma unroll
    for (int j = 0; j < 16; ++j) {
      int c = sc0 + j * 4;
      float4 v = *(const float4*)(P + (size_t)gr * DIM + c);
      As[c + 0][sr] = v.x;
      As[c + 1][sr] = v.y;
      As[c + 2][sr] = v.z;
      As[c + 3][sr] = v.w;
    }
  }
  __syncthreads();
  const int tr = tid >> 4;
  const int tc = tid & 15;
  float acc[8][8];
#pragma unroll
  for (int i = 0; i < 8; ++i)
#pragma unroll
    for (int j = 0; j < 8; ++j) acc[i][j] = 0.f;
#pragma unroll 4
  for (int k = 0; k < DIM; ++k) {
    float a[8], w[8];
    *(float4*)&a[0] = *(const float4*)&As[k][tr * 8];
    *(float4*)&a[4] = *(const float4*)&As[k][tr * 8 + 4];
    *(float4*)&w[0] = *(const float4*)&Wl[k][tc * 4];
    *(float4*)&w[4] = *(const float4*)&Wl[k][64 + tc * 4];
#pragma unroll
    for (int i = 0; i < 8; ++i)
#pragma unroll
      for (int j = 0; j < 8; ++j) acc[i][j] = fmaf(a[i], w[j], acc[i][j]);
  }
  float4 b0 = *(const float4*)(ob + tc * 4);
  float4 b1 = *(const float4*)(ob + 64 + tc * 4);
#pragma unroll
  for (int i = 0; i < 8; ++i) {
    int r = bm + tr * 8 + i;  // 8192 rows exact
    float ic = 1.0f / fmaxf(cnt[r], 1.0f);
    float4 o0, o1;
    o0.x = acc[i][0] * ic + b0.x; o0.y = acc[i][1] * ic + b0.y;
    o0.z = acc[i][2] * ic + b0.z; o0.w = acc[i][3] * ic + b0.w;
    o1.x = acc[i][4] * ic + b1.x; o1.y = acc[i][5] * ic + b1.y;
    o1.z = acc[i][6] * ic + b1.z; o1.w = acc[i][7] * ic + b1.w;
    *(float4*)(out + (size_t)r * DIM + tc * 4) = o0;
    *(float4*)(out + (size_t)r * DIM + 64 + tc * 4) = o1;
  }
}

extern "C" void kernel_launch(void* const* d_in, const int* in_sizes, int n_in,
                              void* d_out, int out_size, void* d_ws, size_t ws_size,
                              hipStream_t stream) {
  const int* xf = (const int*)d_in[0];
  const int* ei = (const int*)d_in[1];
  const int* ea = (const int*)d_in[2];
  const int* batch = (const int*)d_in[3];
  const float* aemb = (const float*)d_in[4];
  const float* bemb = (const float*)d_in[5];
  const float* Wsp = (const float*)d_in[6];
  const float* bsp = (const float*)d_in[7];
  const float* roots = (const float*)d_in[8];
  const float* gamma = (const float*)d_in[9];
  const float* beta = (const float*)d_in[10];
  const float* oW = (const float*)d_in[11];
  const float* ob = (const float*)d_in[12];
  float* out = (float*)d_out;

  // workspace layout (~108.8 MB):
  half_t* AGG = (half_t*)d_ws;                     // [NN*DIM] fp16
  half_t* HB = AGG + (size_t)NN * DIM;             // [NN*DIM] fp16
  float* deg = (float*)(HB + (size_t)NN * DIM);    // [NN]
  float* dinv = deg + NN;                          // [NN]
  float* invdeg = dinv + NN;                       // [NN]
  int* indeg = (int*)(invdeg + NN);                // [NN]
  int* writecur = indeg + NN;                      // [NN]
  int* epk = writecur + NN;                        // [NE]
  int* bsum = epk + NE;                            // [NBLK]
  int* boff = bsum + NBLK;                         // [NBLK]
  // pooled/cnt overlay dead HB at pool time:
  float* pooled = (float*)HB;                      // [NG*DIM]
  float* cnt = pooled + (size_t)NG * DIM;          // [NG]

  k_init<<<(NN + 255) / 256, 256, 0, stream>>>(deg, indeg);
  k_deg<<<(NE + 255) / 256, 256, 0, stream>>>(ei, deg, indeg);
  k_dinv<<<(NN + 255) / 256, 256, 0, stream>>>(deg, dinv, invdeg);
  k_scansum<<<NBLK, 256, 0, stream>>>(indeg, bsum);
  k_scanmid<<<1, 1024, 0, stream>>>(bsum, boff);
  k_scanfinal<<<NBLK, 256, 0, stream>>>(indeg, boff, writecur);
  k_fill<<<(NE + 255) / 256, 256, 0, stream>>>(ei, ea, writecur, epk);
  k_atom<<<NN / 4, 256, 0, stream>>>(xf, aemb, AGG);

  const int gblocks = (NN + DIM - 1) / DIM;  // 1563
  for (int i = 0; i < 5; ++i) {
    const float* W = Wsp + (size_t)i * DIM * DIM;
    const float* bias = bsp + (size_t)i * DIM;
    const float* root = roots + (size_t)i * DIM;
    k_gemm<<<gblocks, 256, 0, stream>>>(AGG, W, bias, HB);
    if (i < 4)
      k_gather<1><<<NN / 8, 256, 0, stream>>>(
          indeg, writecur, epk, bemb + (size_t)i * 3 * BV * DIM, dinv, invdeg,
          root, gamma + (size_t)i * DIM, beta + (size_t)i * DIM, HB, AGG);
    else
      k_gather<0><<<NN / 8, 256, 0, stream>>>(
          indeg, writecur, epk, bemb + (size_t)i * 3 * BV * DIM, dinv, invdeg,
          root, nullptr, nullptr, HB, AGG);
  }
  hipMemsetAsync(pooled, 0, (size_t)(NG * DIM + NG) * sizeof(float), stream);
  k_pool<<<NN / 16, 128, 0, stream>>>(AGG, batch, pooled, cnt);
  k_outgemm<<<NG / DIM, 256, 0, stream>>>(pooled, oW, ob, cnt, out);
}

// Round 13
// 938.210 us; speedup vs baseline: 2.2688x; 1.0957x over previous
//
#include <hip/hip_runtime.h>
#include <hip/hip_fp16.h>

#define NN 200000   // nodes
#define NE 600000   // edges
#define NG 8192     // graphs
#define DIM 128
#define AV 119      // atom vocab
#define BV 5        // bond vocab
#define NBLK 782    // ceil(NN/256) for scan

typedef __half half_t;
typedef _Float16 f16x8 __attribute__((ext_vector_type(8)));
typedef float f32x4 __attribute__((ext_vector_type(4)));

union AF { uint4 u; __half2 h[4]; f16x8 v; _Float16 f[8]; };
union H2 { uint2 u; __half2 h[2]; _Float16 f[4]; };

__device__ inline uint2 pack4h(float a, float b, float c, float d) {
  union { uint2 u; __half2 h[2]; } r;
  r.h[0] = __floats2half2_rn(a, b);
  r.h[1] = __floats2half2_rn(c, d);
  return r.u;
}

// ---------------- init ----------------
__global__ __launch_bounds__(256) void k_init(float* __restrict__ deg,
                                              int* __restrict__ indeg) {
  int i = blockIdx.x * 256 + threadIdx.x;
  if (i < NN) { deg[i] = 1.0f; indeg[i] = 0; }
}

// ---------------- degree (over row) + in-degree (over col) ----------------
__global__ __launch_bounds__(256) void k_deg(const int* __restrict__ ei,
                                             float* __restrict__ deg,
                                             int* __restrict__ indeg) {
  int e = blockIdx.x * 256 + threadIdx.x;
  if (e < NE) {
    unsafeAtomicAdd(&deg[ei[e]], 1.0f);
    atomicAdd(&indeg[ei[NE + e]], 1);
  }
}

__global__ __launch_bounds__(256) void k_dinv(const float* __restrict__ deg,
                                              float* __restrict__ dinv,
                                              float* __restrict__ invdeg) {
  int n = blockIdx.x * 256 + threadIdx.x;
  if (n < NN) {
    float d = deg[n];
    dinv[n] = 1.0f / sqrtf(d);
    invdeg[n] = 1.0f / d;
  }
}

// ---------------- 3-phase exclusive scan of indeg -> writecur ----------------
__global__ __launch_bounds__(256) void k_scansum(const int* __restrict__ indeg,
                                                 int* __restrict__ bsum) {
  __shared__ int s[256];
  int i = blockIdx.x * 256 + threadIdx.x;
  int v = (i < NN) ? indeg[i] : 0;
  s[threadIdx.x] = v;
  __syncthreads();
  for (int off = 128; off > 0; off >>= 1) {
    if (threadIdx.x < off) s[threadIdx.x] += s[threadIdx.x + off];
    __syncthreads();
  }
  if (threadIdx.x == 0) bsum[blockIdx.x] = s[0];
}

__global__ __launch_bounds__(1024) void k_scanmid(const int* __restrict__ bsum,
                                                  int* __restrict__ boff) {
  __shared__ int s[1024];
  int t = threadIdx.x;
  int v = (t < NBLK) ? bsum[t] : 0;
  s[t] = v;
  __syncthreads();
  for (int off = 1; off < 1024; off <<= 1) {
    int x = (t >= off) ? s[t - off] : 0;
    __syncthreads();
    s[t] += x;
    __syncthreads();
  }
  if (t < NBLK) boff[t] = s[t] - v;
}

__global__ __launch_bounds__(256) void k_scanfinal(const int* __restrict__ indeg,
                                                   const int* __restrict__ boff,
                                                   int* __restrict__ writecur) {
  __shared__ int s[256];
  int i = blockIdx.x * 256 + threadIdx.x;
  int v = (i < NN) ? indeg[i] : 0;
  s[threadIdx.x] = v;
  __syncthreads();
  for (int off = 1; off < 256; off <<= 1) {
    int x = (threadIdx.x >= off) ? s[threadIdx.x - off] : 0;
    __syncthreads();
    s[threadIdx.x] += x;
    __syncthreads();
  }
  if (i < NN) writecur[i] = s[threadIdx.x] - v + boff[blockIdx.x];
}

// ---------------- fill CSR: epk2[pos] = {row|a0<<18|a1<<21|a2<<24, norm} ----------------
__global__ __launch_bounds__(256) void k_fill(const int* __restrict__ ei,
                                              const int* __restrict__ ea,
                                              const float* __restrict__ dinv,
                                              int* __restrict__ writecur,
                                              uint2* __restrict__ epk2) {
  int e = blockIdx.x * 256 + threadIdx.x;
  if (e >= NE) return;
  int row = ei[e];
  int col = ei[NE + e];
  int pos = atomicAdd(&writecur[col], 1);
  float nr = dinv[row] * dinv[col];
  uint pk = (uint)row | ((uint)ea[e * 3] << 18) | ((uint)ea[e * 3 + 1] << 21) |
            ((uint)ea[e * 3 + 2] << 24);
  epk2[pos] = make_uint2(pk, __float_as_uint(nr));
}

// ---------------- AtomEncoder ----------------
__global__ __launch_bounds__(256) void k_atom(const int* __restrict__ xf,
                                              const float* __restrict__ aemb,
                                              half_t* __restrict__ A) {
  int n = blockIdx.x * 4 + (threadIdx.x >> 6);
  int d = (threadIdx.x & 63) * 2;
  float sx = 0.f, sy = 0.f;
#pragma unroll
  for (int c = 0; c < 9; ++c) {
    int idx = xf[n * 9 + c];
    float2 v = *(const float2*)(aemb + (size_t)(c * AV + idx) * DIM + d);
    sx += v.x; sy += v.y;
  }
  *(__half2*)(A + (size_t)n * DIM + d) = __floats2half2_rn(sx, sy);
}

// ---------------- W hi/lo split into MFMA fragment order (one-time) ----------------
// fragment index for (k,col): k=ks*32+kg*8+j -> ((ks*128+col)*32 + kg*8 + j)
__global__ __launch_bounds__(256) void k_wsplit(const float* __restrict__ Wsp,
                                                half_t* __restrict__ Wfh,
                                                half_t* __restrict__ Wfl) {
  int gid = blockIdx.x * 256 + threadIdx.x;  // 5*16384 total
  int l = gid >> 14;
  int r = gid & 16383;
  int k = r >> 7, col = r & 127;
  float w = Wsp[gid];
  _Float16 hi = (_Float16)w;
  _Float16 lo = (_Float16)(w - (float)hi);
  int ks = k >> 5, kg = (k >> 3) & 3, j = k & 7;
  int fi = (l << 14) | ((ks * 128 + col) * 32 + kg * 8 + j);
  *(_Float16*)&Wfh[fi] = hi;
  *(_Float16*)&Wfl[fi] = lo;
}

// ---------------- MFMA layer GEMM: HB = AGG @ W + bias ----------------
// W fragments pre-packed (hi/lo fp16) -> coalesced uint4 loads, no scalar prologue.
__global__ __launch_bounds__(256) void k_gemm(
    const half_t* __restrict__ Ain, const half_t* __restrict__ Wfh,
    const half_t* __restrict__ Wfl, const float* __restrict__ bias,
    half_t* __restrict__ HB) {
  const int tid = threadIdx.x;
  const int lane = tid & 63;
  const int wave = tid >> 6;
  const int bm = blockIdx.x * DIM;
  const int lr = lane & 15;
  const int kg = lane >> 4;
  const int n0 = wave * 32;

  f16x8 wh[2][4], wl[2][4];
#pragma unroll
  for (int nt = 0; nt < 2; ++nt) {
    const int col = n0 + nt * 16 + lr;
#pragma unroll
    for (int ks = 0; ks < 4; ++ks) {
      const int fi = (ks * 128 + col) * 32 + kg * 8;
      wh[nt][ks] = *(const f16x8*)(Wfh + fi);
      wl[nt][ks] = *(const f16x8*)(Wfl + fi);
    }
  }

  f32x4 acc[8][2];
#pragma unroll
  for (int mt = 0; mt < 8; ++mt)
#pragma unroll
    for (int nt = 0; nt < 2; ++nt) acc[mt][nt] = (f32x4){0.f, 0.f, 0.f, 0.f};

#pragma unroll
  for (int ks = 0; ks < 4; ++ks) {
    const int kb = ks * 32 + kg * 8;
    AF a[8];
#pragma unroll
    for (int mt = 0; mt < 8; ++mt) {
      const int row = bm + mt * 16 + lr;
      if (row < NN)
        a[mt].u = *(const uint4*)(Ain + (size_t)row * DIM + kb);
      else
        a[mt].u = make_uint4(0u, 0u, 0u, 0u);
    }
#pragma unroll
    for (int mt = 0; mt < 8; ++mt)
#pragma unroll
      for (int nt = 0; nt < 2; ++nt) {
        acc[mt][nt] = __builtin_amdgcn_mfma_f32_16x16x32_f16(
            a[mt].v, wh[nt][ks], acc[mt][nt], 0, 0, 0);
        acc[mt][nt] = __builtin_amdgcn_mfma_f32_16x16x32_f16(
            a[mt].v, wl[nt][ks], acc[mt][nt], 0, 0, 0);
      }
  }

#pragma unroll
  for (int nt = 0; nt < 2; ++nt) {
    const int col = n0 + nt * 16 + lr;
    const float bv = bias[col];
#pragma unroll
    for (int mt = 0; mt < 8; ++mt) {
#pragma unroll
      for (int r = 0; r < 4; ++r) {
        const int row = bm + mt * 16 + kg * 4 + r;
        if (row < NN)
          HB[(size_t)row * DIM + col] = __float2half(acc[mt][nt][r] + bv);
      }
    }
  }
}

// ---------------- gather: 8-edge chunks, MLP=8, scalar _Float16 math ----------------
// AGG[n] = act( relu(HB[n]+root)*invdeg[n] + sum_e norm_e * relu16(HB[row_e]+ee_e) )
template <int ACT>
__global__ __launch_bounds__(256) void k_gather(
    const int* __restrict__ indeg, const int* __restrict__ wend,
    const uint2* __restrict__ epk2, const float* __restrict__ bond,
    const float* __restrict__ invdeg, const float* __restrict__ root,
    const float* __restrict__ gamma, const float* __restrict__ beta,
    const half_t* __restrict__ HB, half_t* __restrict__ AGG) {
  __shared__ __align__(8) half_t bl16[3 * BV * DIM];  // 3.84 KB fp16
  for (int i = threadIdx.x; i < 3 * BV * DIM; i += 256)
    bl16[i] = __float2half(bond[i]);
  __syncthreads();
  const int lane = threadIdx.x & 63;
  const int n = blockIdx.x * 8 + (threadIdx.x >> 5);
  const int d = (threadIdx.x & 31) * 4;
  const int t8 = lane & 7;
  const int sbase = lane & 32;

  // self-term (fp32)
  H2 hu; hu.u = *(const uint2*)(HB + (size_t)n * DIM + d);
  float2 slo = __half22float2(hu.h[0]);
  float2 shi = __half22float2(hu.h[1]);
  float4 rt = *(const float4*)(root + d);
  const float idg = invdeg[n];
  float a0 = fmaxf(slo.x + rt.x, 0.f) * idg;
  float a1 = fmaxf(slo.y + rt.y, 0.f) * idg;
  float a2 = fmaxf(shi.x + rt.z, 0.f) * idg;
  float a3 = fmaxf(shi.y + rt.w, 0.f) * idg;

  int cnt = indeg[n];
  int base = wend[n] - cnt;
  while (cnt > 0) {
    const int m = min(cnt, 8);
    uint2 ev = make_uint2(0u, 0u);
    if (t8 < m) ev = epk2[base + t8];
    int pkx[8]; float nrx[8]; uint2 hx[8];
#pragma unroll
    for (int t = 0; t < 8; ++t) {
      pkx[t] = __shfl((int)ev.x, sbase | t, 64);
      nrx[t] = __uint_as_float(__shfl((int)ev.y, sbase | t, 64));
      if (t < m)
        hx[t] = *(const uint2*)(HB + (size_t)(pkx[t] & 0x3FFFF) * DIM + d);
    }
#pragma unroll
    for (int t = 0; t < 8; ++t) {
      if (t < m) {
        int pk = pkx[t];
        H2 hh; hh.u = hx[t];
        H2 b0; b0.u = *(const uint2*)&bl16[(((pk >> 18) & 7)) * DIM + d];
        H2 b1; b1.u = *(const uint2*)&bl16[(BV + ((pk >> 21) & 7)) * DIM + d];
        H2 b2; b2.u = *(const uint2*)&bl16[(2 * BV + ((pk >> 24) & 7)) * DIM + d];
        float s[4];
#pragma unroll
        for (int q = 0; q < 4; ++q) {
          _Float16 v = (_Float16)(hh.f[q] + b0.f[q] + b1.f[q] + b2.f[q]);
          v = (v > (_Float16)0) ? v : (_Float16)0;
          s[q] = (float)v;
        }
        float nr = nrx[t];
        a0 = fmaf(s[0], nr, a0);
        a1 = fmaf(s[1], nr, a1);
        a2 = fmaf(s[2], nr, a2);
        a3 = fmaf(s[3], nr, a3);
      }
    }
    base += 8;
    cnt -= 8;
  }
  if (ACT) {
    const float bns = rsqrtf(1.0f + 1e-5f);
    float4 g = *(const float4*)(gamma + d);
    float4 be = *(const float4*)(beta + d);
    a0 = fmaxf(fmaf(a0, g.x * bns, be.x), 0.f);
    a1 = fmaxf(fmaf(a1, g.y * bns, be.y), 0.f);
    a2 = fmaxf(fmaf(a2, g.z * bns, be.z), 0.f);
    a3 = fmaxf(fmaf(a3, g.w * bns, be.w), 0.f);
  }
  *(uint2*)(AGG + (size_t)n * DIM + d) = pack4h(a0, a1, a2, a3);
}

// ---------------- pooling ----------------
__global__ __launch_bounds__(128) void k_pool(const half_t* __restrict__ A,
                                              const int* __restrict__ batch,
                                              float* __restrict__ pooled,
                                              float* __restrict__ cnt) {
  const int d = threadIdx.x;
  const int base = blockIdx.x * 16;
  int curb = batch[base];
  float acc = 0.f, cacc = 0.f;
#pragma unroll
  for (int i = 0; i < 16; ++i) {
    int n = base + i;
    int b = batch[n];
    if (b != curb) {
      unsafeAtomicAdd(&pooled[(size_t)curb * DIM + d], acc);
      if (d == 0) unsafeAtomicAdd(&cnt[curb], cacc);
      curb = b; acc = 0.f; cacc = 0.f;
    }
    acc += __half2float(A[(size_t)n * DIM + d]);
    cacc += 1.f;
  }
  unsafeAtomicAdd(&pooled[(size_t)curb * DIM + d], acc);
  if (d == 0) unsafeAtomicAdd(&cnt[curb], cacc);
}

// ---------------- output GEMM ----------------
__global__ __launch_bounds__(256) void k_outgemm(const float* __restrict__ P,
                                                 const float* __restrict__ W,
                                                 const float* __restrict__ ob,
                                                 const float* __restrict__ cnt,
                                                 float* __restrict__ out) {
  __shared__ __align__(16) float As[DIM][DIM];
  __shared__ __align__(16) float Wl[DIM][DIM];
  const int tid = threadIdx.x;
  const int bm = blockIdx.x * DIM;
#pragma unroll
  for (int it = 0; it < 16; ++it) {
    int idx = it * 256 + tid;
    ((float4*)&Wl[0][0])[idx] = ((const float4*)W)[idx];
  }
  {
    const int sr = tid >> 1;
    const int sc0 = (tid & 1) * 64;
    const int gr = bm + sr;
#pragma unroll
    for (int j = 0; j < 16; ++j) {
      int c = sc0 + j * 4;
      float4 v = *(const float4*)(P + (size_t)gr * DIM + c);
      As[c + 0][sr] = v.x;
      As[c + 1][sr] = v.y;
      As[c + 2][sr] = v.z;
      As[c + 3][sr] = v.w;
    }
  }
  __syncthreads();
  const int tr = tid >> 4;
  const int tc = tid & 15;
  float acc[8][8];
#pragma unroll
  for (int i = 0; i < 8; ++i)
#pragma unroll
    for (int j = 0; j < 8; ++j) acc[i][j] = 0.f;
#pragma unroll 4
  for (int k = 0; k < DIM; ++k) {
    float a[8], w[8];
    *(float4*)&a[0] = *(const float4*)&As[k][tr * 8];
    *(float4*)&a[4] = *(const float4*)&As[k][tr * 8 + 4];
    *(float4*)&w[0] = *(const float4*)&Wl[k][tc * 4];
    *(float4*)&w[4] = *(const float4*)&Wl[k][64 + tc * 4];
#pragma unroll
    for (int i = 0; i < 8; ++i)
#pragma unroll
      for (int j = 0; j < 8; ++j) acc[i][j] = fmaf(a[i], w[j], acc[i][j]);
  }
  float4 b0 = *(const float4*)(ob + tc * 4);
  float4 b1 = *(const float4*)(ob + 64 + tc * 4);
#pragma unroll
  for (int i = 0; i < 8; ++i) {
    int r = bm + tr * 8 + i;  // 8192 rows exact
    float ic = 1.0f / fmaxf(cnt[r], 1.0f);
    float4 o0, o1;
    o0.x = acc[i][0] * ic + b0.x; o0.y = acc[i][1] * ic + b0.y;
    o0.z = acc[i][2] * ic + b0.z; o0.w = acc[i][3] * ic + b0.w;
    o1.x = acc[i][4] * ic + b1.x; o1.y = acc[i][5] * ic + b1.y;
    o1.z = acc[i][6] * ic + b1.z; o1.w = acc[i][7] * ic + b1.w;
    *(float4*)(out + (size_t)r * DIM + tc * 4) = o0;
    *(float4*)(out + (size_t)r * DIM + 64 + tc * 4) = o1;
  }
}

extern "C" void kernel_launch(void* const* d_in, const int* in_sizes, int n_in,
                              void* d_out, int out_size, void* d_ws, size_t ws_size,
                              hipStream_t stream) {
  const int* xf = (const int*)d_in[0];
  const int* ei = (const int*)d_in[1];
  const int* ea = (const int*)d_in[2];
  const int* batch = (const int*)d_in[3];
  const float* aemb = (const float*)d_in[4];
  const float* bemb = (const float*)d_in[5];
  const float* Wsp = (const float*)d_in[6];
  const float* bsp = (const float*)d_in[7];
  const float* roots = (const float*)d_in[8];
  const float* gamma = (const float*)d_in[9];
  const float* beta = (const float*)d_in[10];
  const float* oW = (const float*)d_in[11];
  const float* ob = (const float*)d_in[12];
  float* out = (float*)d_out;

  // workspace layout (~111.5 MB):
  half_t* AGG = (half_t*)d_ws;                     // [NN*DIM] fp16
  half_t* HB = AGG + (size_t)NN * DIM;             // [NN*DIM] fp16
  float* deg = (float*)(HB + (size_t)NN * DIM);    // [NN]
  float* dinv = deg + NN;                          // [NN]
  float* invdeg = dinv + NN;                       // [NN]
  int* indeg = (int*)(invdeg + NN);                // [NN]
  int* writecur = indeg + NN;                      // [NN]
  uint2* epk2 = (uint2*)(writecur + NN);           // [NE] 8B each
  int* bsum = (int*)(epk2 + NE);                   // [NBLK]
  int* boff = bsum + NBLK;                         // [NBLK]
  half_t* Wfh = (half_t*)(boff + NBLK);            // [5*16384]
  half_t* Wfl = Wfh + 5 * 16384;                   // [5*16384]
  // pooled/cnt overlay dead HB at pool time:
  float* pooled = (float*)HB;                      // [NG*DIM]
  float* cnt = pooled + (size_t)NG * DIM;          // [NG]

  k_init<<<(NN + 255) / 256, 256, 0, stream>>>(deg, indeg);
  k_deg<<<(NE + 255) / 256, 256, 0, stream>>>(ei, deg, indeg);
  k_dinv<<<(NN + 255) / 256, 256, 0, stream>>>(deg, dinv, invdeg);
  k_scansum<<<NBLK, 256, 0, stream>>>(indeg, bsum);
  k_scanmid<<<1, 1024, 0, stream>>>(bsum, boff);
  k_scanfinal<<<NBLK, 256, 0, stream>>>(indeg, boff, writecur);
  k_fill<<<(NE + 255) / 256, 256, 0, stream>>>(ei, ea, dinv, writecur, epk2);
  k_wsplit<<<5 * 16384 / 256, 256, 0, stream>>>(Wsp, Wfh, Wfl);
  k_atom<<<NN / 4, 256, 0, stream>>>(xf, aemb, AGG);

  const int gblocks = (NN + DIM - 1) / DIM;  // 1563
  for (int i = 0; i < 5; ++i) {
    const float* bias = bsp + (size_t)i * DIM;
    const float* root = roots + (size_t)i * DIM;
    k_gemm<<<gblocks, 256, 0, stream>>>(AGG, Wfh + (size_t)i * 16384,
                                        Wfl + (size_t)i * 16384, bias, HB);
    if (i < 4)
      k_gather<1><<<NN / 8, 256, 0, stream>>>(
          indeg, writecur, epk2, bemb + (size_t)i * 3 * BV * DIM, invdeg, root,
          gamma + (size_t)i * DIM, beta + (size_t)i * DIM, HB, AGG);
    else
      k_gather<0><<<NN / 8, 256, 0, stream>>>(
          indeg, writecur, epk2, bemb + (size_t)i * 3 * BV * DIM, invdeg, root,
          nullptr, nullptr, HB, AGG);
  }
  (void)hipMemsetAsync(pooled, 0, (size_t)(NG * DIM + NG) * sizeof(float), stream);
  k_pool<<<NN / 16, 128, 0, stream>>>(AGG, batch, pooled, cnt);
  k_outgemm<<<NG / DIM, 256, 0, stream>>>(pooled, oW, ob, cnt, out);
}

// Round 14
// 820.843 us; speedup vs baseline: 2.5933x; 1.1430x over previous
//
#include <hip/hip_runtime.h>
#include <hip/hip_fp16.h>

#define NN 200000   // nodes
#define NE 600000   // edges
#define NG 8192     // graphs
#define DIM 128
#define AV 119      // atom vocab
#define BV 5        // bond vocab
#define NBLK 782    // ceil(NN/256) for scan

typedef __half half_t;
typedef _Float16 f16x8 __attribute__((ext_vector_type(8)));
typedef float f32x4 __attribute__((ext_vector_type(4)));

union AF { uint4 u; __half2 h[4]; f16x8 v; _Float16 f[8]; };
union H2 { uint2 u; __half2 h[2]; _Float16 f[4]; };

__device__ inline uint2 pack4h(float a, float b, float c, float d) {
  union { uint2 u; __half2 h[2]; } r;
  r.h[0] = __floats2half2_rn(a, b);
  r.h[1] = __floats2half2_rn(c, d);
  return r.u;
}

// ---------------- init ----------------
__global__ __launch_bounds__(256) void k_init(float* __restrict__ deg,
                                              int* __restrict__ indeg) {
  int i = blockIdx.x * 256 + threadIdx.x;
  if (i < NN) { deg[i] = 1.0f; indeg[i] = 0; }
}

// ---------------- degree (over row) + in-degree (over col) ----------------
__global__ __launch_bounds__(256) void k_deg(const int* __restrict__ ei,
                                             float* __restrict__ deg,
                                             int* __restrict__ indeg) {
  int e = blockIdx.x * 256 + threadIdx.x;
  if (e < NE) {
    unsafeAtomicAdd(&deg[ei[e]], 1.0f);
    atomicAdd(&indeg[ei[NE + e]], 1);
  }
}

__global__ __launch_bounds__(256) void k_dinv(const float* __restrict__ deg,
                                              float* __restrict__ dinv,
                                              float* __restrict__ invdeg) {
  int n = blockIdx.x * 256 + threadIdx.x;
  if (n < NN) {
    float d = deg[n];
    dinv[n] = 1.0f / sqrtf(d);
    invdeg[n] = 1.0f / d;
  }
}

// ---------------- 3-phase exclusive scan of indeg -> writecur ----------------
__global__ __launch_bounds__(256) void k_scansum(const int* __restrict__ indeg,
                                                 int* __restrict__ bsum) {
  __shared__ int s[256];
  int i = blockIdx.x * 256 + threadIdx.x;
  int v = (i < NN) ? indeg[i] : 0;
  s[threadIdx.x] = v;
  __syncthreads();
  for (int off = 128; off > 0; off >>= 1) {
    if (threadIdx.x < off) s[threadIdx.x] += s[threadIdx.x + off];
    __syncthreads();
  }
  if (threadIdx.x == 0) bsum[blockIdx.x] = s[0];
}

__global__ __launch_bounds__(1024) void k_scanmid(const int* __restrict__ bsum,
                                                  int* __restrict__ boff) {
  __shared__ int s[1024];
  int t = threadIdx.x;
  int v = (t < NBLK) ? bsum[t] : 0;
  s[t] = v;
  __syncthreads();
  for (int off = 1; off < 1024; off <<= 1) {
    int x = (t >= off) ? s[t - off] : 0;
    __syncthreads();
    s[t] += x;
    __syncthreads();
  }
  if (t < NBLK) boff[t] = s[t] - v;
}

__global__ __launch_bounds__(256) void k_scanfinal(const int* __restrict__ indeg,
                                                   const int* __restrict__ boff,
                                                   int* __restrict__ writecur) {
  __shared__ int s[256];
  int i = blockIdx.x * 256 + threadIdx.x;
  int v = (i < NN) ? indeg[i] : 0;
  s[threadIdx.x] = v;
  __syncthreads();
  for (int off = 1; off < 256; off <<= 1) {
    int x = (threadIdx.x >= off) ? s[threadIdx.x - off] : 0;
    __syncthreads();
    s[threadIdx.x] += x;
    __syncthreads();
  }
  if (i < NN) writecur[i] = s[threadIdx.x] - v + boff[blockIdx.x];
}

// ---------------- fill CSR: epk2[pos] = {row|a0<<18|a1<<21|a2<<24, norm} ----------------
__global__ __launch_bounds__(256) void k_fill(const int* __restrict__ ei,
                                              const int* __restrict__ ea,
                                              const float* __restrict__ dinv,
                                              int* __restrict__ writecur,
                                              uint2* __restrict__ epk2) {
  int e = blockIdx.x * 256 + threadIdx.x;
  if (e >= NE) return;
  int row = ei[e];
  int col = ei[NE + e];
  int pos = atomicAdd(&writecur[col], 1);
  float nr = dinv[row] * dinv[col];
  uint pk = (uint)row | ((uint)ea[e * 3] << 18) | ((uint)ea[e * 3 + 1] << 21) |
            ((uint)ea[e * 3 + 2] << 24);
  epk2[pos] = make_uint2(pk, __float_as_uint(nr));
}

// ---------------- AtomEncoder: 32 threads/node, float4 gathers ----------------
__global__ __launch_bounds__(256) void k_atom(const int* __restrict__ xf,
                                              const float* __restrict__ aemb,
                                              half_t* __restrict__ A) {
  int n = blockIdx.x * 8 + (threadIdx.x >> 5);
  int d = (threadIdx.x & 31) * 4;
  float s0 = 0.f, s1 = 0.f, s2 = 0.f, s3 = 0.f;
#pragma unroll
  for (int c = 0; c < 9; ++c) {
    int idx = xf[n * 9 + c];
    float4 v = *(const float4*)(aemb + (size_t)(c * AV + idx) * DIM + d);
    s0 += v.x; s1 += v.y; s2 += v.z; s3 += v.w;
  }
  *(uint2*)(A + (size_t)n * DIM + d) = pack4h(s0, s1, s2, s3);
}

// ---------------- W hi/lo split into swapped-operand MFMA fragment order ----------------
// For mfma A-operand = W^T fragment: element (k,col) with ks=k>>5, kg=(k>>3)&3,
// j=k&7, mt=col>>4, lr=col&15 -> fi = (ks*8+mt)*512 + kg*128 + lr*8 + j.
__global__ __launch_bounds__(256) void k_wsplit(const float* __restrict__ Wsp,
                                                half_t* __restrict__ Wfh,
                                                half_t* __restrict__ Wfl) {
  int gid = blockIdx.x * 256 + threadIdx.x;  // 5*16384 total
  int l = gid >> 14;
  int r = gid & 16383;
  int k = r >> 7, col = r & 127;
  float w = Wsp[gid];
  _Float16 hi = (_Float16)w;
  _Float16 lo = (_Float16)(w - (float)hi);
  int ks = k >> 5, kg = (k >> 3) & 3, j = k & 7;
  int mt = col >> 4, lr = col & 15;
  int fi = (l << 14) | ((ks * 8 + mt) * 512 + kg * 128 + lr * 8 + j);
  *(_Float16*)&Wfh[fi] = hi;
  *(_Float16*)&Wfl[fi] = lo;
}

// ---------------- MFMA layer GEMM: HB = AGG @ W + bias (swapped operands) ----------------
// Wave owns 32 rows x 128 cols. W as A-operand, nodes as B-operand:
// D col(lane&15)=node, row(kg*4+r)=feature -> 4 consecutive features/lane -> uint2 stores.
__global__ __launch_bounds__(256) void k_gemm(
    const half_t* __restrict__ Ain, const half_t* __restrict__ Wfh,
    const half_t* __restrict__ Wfl, const float* __restrict__ bias,
    half_t* __restrict__ HB) {
  const int tid = threadIdx.x;
  const int lane = tid & 63;
  const int wave = tid >> 6;
  const int lr = lane & 15;
  const int kg = lane >> 4;
  const int n0 = blockIdx.x * DIM + wave * 32;

  f32x4 acc[8][2];
#pragma unroll
  for (int mt = 0; mt < 8; ++mt)
#pragma unroll
    for (int nt = 0; nt < 2; ++nt) acc[mt][nt] = (f32x4){0.f, 0.f, 0.f, 0.f};

#pragma unroll
  for (int ks = 0; ks < 4; ++ks) {
    const int kb = ks * 32 + kg * 8;
    AF b[2];
#pragma unroll
    for (int nt = 0; nt < 2; ++nt) {
      const int row = n0 + nt * 16 + lr;
      if (row < NN)
        b[nt].u = *(const uint4*)(Ain + (size_t)row * DIM + kb);
      else
        b[nt].u = make_uint4(0u, 0u, 0u, 0u);
    }
#pragma unroll
    for (int mt = 0; mt < 8; ++mt) {
      const int fi = (ks * 8 + mt) * 512 + kg * 128 + lr * 8;
      f16x8 wh = *(const f16x8*)(Wfh + fi);
      f16x8 wl = *(const f16x8*)(Wfl + fi);
#pragma unroll
      for (int nt = 0; nt < 2; ++nt) {
        acc[mt][nt] = __builtin_amdgcn_mfma_f32_16x16x32_f16(
            wh, b[nt].v, acc[mt][nt], 0, 0, 0);
        acc[mt][nt] = __builtin_amdgcn_mfma_f32_16x16x32_f16(
            wl, b[nt].v, acc[mt][nt], 0, 0, 0);
      }
    }
  }

  // epilogue: lane holds node = n0+nt*16+lr, features mt*16+kg*4+{0..3}
#pragma unroll
  for (int mt = 0; mt < 8; ++mt) {
    const int f0 = mt * 16 + kg * 4;
    float4 bv = *(const float4*)(bias + f0);
#pragma unroll
    for (int nt = 0; nt < 2; ++nt) {
      const int node = n0 + nt * 16 + lr;
      if (node < NN)
        *(uint2*)(HB + (size_t)node * DIM + f0) =
            pack4h(acc[mt][nt][0] + bv.x, acc[mt][nt][1] + bv.y,
                   acc[mt][nt][2] + bv.z, acc[mt][nt][3] + bv.w);
    }
  }
}

// ---------------- gather: 8-edge chunks, MLP=8, scalar _Float16 math ----------------
// AGG[n] = act( relu(HB[n]+root)*invdeg[n] + sum_e norm_e * relu16(HB[row_e]+ee_e) )
template <int ACT>
__global__ __launch_bounds__(256) void k_gather(
    const int* __restrict__ indeg, const int* __restrict__ wend,
    const uint2* __restrict__ epk2, const float* __restrict__ bond,
    const float* __restrict__ invdeg, const float* __restrict__ root,
    const float* __restrict__ gamma, const float* __restrict__ beta,
    const half_t* __restrict__ HB, half_t* __restrict__ AGG) {
  __shared__ __align__(8) half_t bl16[3 * BV * DIM];  // 3.84 KB fp16
  for (int i = threadIdx.x; i < 3 * BV * DIM; i += 256)
    bl16[i] = __float2half(bond[i]);
  __syncthreads();
  const int lane = threadIdx.x & 63;
  const int n = blockIdx.x * 8 + (threadIdx.x >> 5);
  const int d = (threadIdx.x & 31) * 4;
  const int t8 = lane & 7;
  const int sbase = lane & 32;

  // self-term (fp32)
  H2 hu; hu.u = *(const uint2*)(HB + (size_t)n * DIM + d);
  float2 slo = __half22float2(hu.h[0]);
  float2 shi = __half22float2(hu.h[1]);
  float4 rt = *(const float4*)(root + d);
  const float idg = invdeg[n];
  float a0 = fmaxf(slo.x + rt.x, 0.f) * idg;
  float a1 = fmaxf(slo.y + rt.y, 0.f) * idg;
  float a2 = fmaxf(shi.x + rt.z, 0.f) * idg;
  float a3 = fmaxf(shi.y + rt.w, 0.f) * idg;

  int cnt = indeg[n];
  int base = wend[n] - cnt;
  while (cnt > 0) {
    const int m = min(cnt, 8);
    uint2 ev = make_uint2(0u, 0u);
    if (t8 < m) ev = epk2[base + t8];
    int pkx[8]; float nrx[8]; uint2 hx[8];
#pragma unroll
    for (int t = 0; t < 8; ++t) {
      pkx[t] = __shfl((int)ev.x, sbase | t, 64);
      nrx[t] = __uint_as_float(__shfl((int)ev.y, sbase | t, 64));
      if (t < m)
        hx[t] = *(const uint2*)(HB + (size_t)(pkx[t] & 0x3FFFF) * DIM + d);
    }
#pragma unroll
    for (int t = 0; t < 8; ++t) {
      if (t < m) {
        int pk = pkx[t];
        H2 hh; hh.u = hx[t];
        H2 b0; b0.u = *(const uint2*)&bl16[(((pk >> 18) & 7)) * DIM + d];
        H2 b1; b1.u = *(const uint2*)&bl16[(BV + ((pk >> 21) & 7)) * DIM + d];
        H2 b2; b2.u = *(const uint2*)&bl16[(2 * BV + ((pk >> 24) & 7)) * DIM + d];
        float s[4];
#pragma unroll
        for (int q = 0; q < 4; ++q) {
          _Float16 v = (_Float16)(hh.f[q] + b0.f[q] + b1.f[q] + b2.f[q]);
          v = (v > (_Float16)0) ? v : (_Float16)0;
          s[q] = (float)v;
        }
        float nr = nrx[t];
        a0 = fmaf(s[0], nr, a0);
        a1 = fmaf(s[1], nr, a1);
        a2 = fmaf(s[2], nr, a2);
        a3 = fmaf(s[3], nr, a3);
      }
    }
    base += 8;
    cnt -= 8;
  }
  if (ACT) {
    const float bns = rsqrtf(1.0f + 1e-5f);
    float4 g = *(const float4*)(gamma + d);
    float4 be = *(const float4*)(beta + d);
    a0 = fmaxf(fmaf(a0, g.x * bns, be.x), 0.f);
    a1 = fmaxf(fmaf(a1, g.y * bns, be.y), 0.f);
    a2 = fmaxf(fmaf(a2, g.z * bns, be.z), 0.f);
    a3 = fmaxf(fmaf(a3, g.w * bns, be.w), 0.f);
  }
  *(uint2*)(AGG + (size_t)n * DIM + d) = pack4h(a0, a1, a2, a3);
}

// ---------------- pooling ----------------
__global__ __launch_bounds__(128) void k_pool(const half_t* __restrict__ A,
                                              const int* __restrict__ batch,
                                              float* __restrict__ pooled,
                                              float* __restrict__ cnt) {
  const int d = threadIdx.x;
  const int base = blockIdx.x * 16;
  int curb = batch[base];
  float acc = 0.f, cacc = 0.f;
#pragma unroll
  for (int i = 0; i < 16; ++i) {
    int n = base + i;
    int b = batch[n];
    if (b != curb) {
      unsafeAtomicAdd(&pooled[(size_t)curb * DIM + d], acc);
      if (d == 0) unsafeAtomicAdd(&cnt[curb], cacc);
      curb = b; acc = 0.f; cacc = 0.f;
    }
    acc += __half2float(A[(size_t)n * DIM + d]);
    cacc += 1.f;
  }
  unsafeAtomicAdd(&pooled[(size_t)curb * DIM + d], acc);
  if (d == 0) unsafeAtomicAdd(&cnt[curb], cacc);
}

// ---------------- output GEMM ----------------
__global__ __launch_bounds__(256) void k_outgemm(const float* __restrict__ P,
                                                 const float* __restrict__ W,
                                                 const float* __restrict__ ob,
                                                 const float* __restrict__ cnt,
                                                 float* __restrict__ out) {
  __shared__ __align__(16) float As[DIM][DIM];
  __shared__ __align__(16) float Wl[DIM][DIM];
  const int tid = threadIdx.x;
  const int bm = blockIdx.x * DIM;
#pragma unroll
  for (int it = 0; it < 16; ++it) {
    int idx = it * 256 + tid;
    ((float4*)&Wl[0][0])[idx] = ((const float4*)W)[idx];
  }
  {
    const int sr = tid >> 1;
    const int sc0 = (tid & 1) * 64;
    const int gr = bm + sr;
#pragma unroll
    for (int j = 0; j < 16; ++j) {
      int c = sc0 + j * 4;
      float4 v = *(const float4*)(P + (size_t)gr * DIM + c);
      As[c + 0][sr] = v.x;
      As[c + 1][sr] = v.y;
      As[c + 2][sr] = v.z;
      As[c + 3][sr] = v.w;
    }
  }
  __syncthreads();
  const int tr = tid >> 4;
  const int tc = tid & 15;
  float acc[8][8];
#pragma unroll
  for (int i = 0; i < 8; ++i)
#pragma unroll
    for (int j = 0; j < 8; ++j) acc[i][j] = 0.f;
#pragma unroll 4
  for (int k = 0; k < DIM; ++k) {
    float a[8], w[8];
    *(float4*)&a[0] = *(const float4*)&As[k][tr * 8];
    *(float4*)&a[4] = *(const float4*)&As[k][tr * 8 + 4];
    *(float4*)&w[0] = *(const float4*)&Wl[k][tc * 4];
    *(float4*)&w[4] = *(const float4*)&Wl[k][64 + tc * 4];
#pragma unroll
    for (int i = 0; i < 8; ++i)
#pragma unroll
      for (int j = 0; j < 8; ++j) acc[i][j] = fmaf(a[i], w[j], acc[i][j]);
  }
  float4 b0 = *(const float4*)(ob + tc * 4);
  float4 b1 = *(const float4*)(ob + 64 + tc * 4);
#pragma unroll
  for (int i = 0; i < 8; ++i) {
    int r = bm + tr * 8 + i;  // 8192 rows exact
    float ic = 1.0f / fmaxf(cnt[r], 1.0f);
    float4 o0, o1;
    o0.x = acc[i][0] * ic + b0.x; o0.y = acc[i][1] * ic + b0.y;
    o0.z = acc[i][2] * ic + b0.z; o0.w = acc[i][3] * ic + b0.w;
    o1.x = acc[i][4] * ic + b1.x; o1.y = acc[i][5] * ic + b1.y;
    o1.z = acc[i][6] * ic + b1.z; o1.w = acc[i][7] * ic + b1.w;
    *(float4*)(out + (size_t)r * DIM + tc * 4) = o0;
    *(float4*)(out + (size_t)r * DIM + 64 + tc * 4) = o1;
  }
}

extern "C" void kernel_launch(void* const* d_in, const int* in_sizes, int n_in,
                              void* d_out, int out_size, void* d_ws, size_t ws_size,
                              hipStream_t stream) {
  const int* xf = (const int*)d_in[0];
  const int* ei = (const int*)d_in[1];
  const int* ea = (const int*)d_in[2];
  const int* batch = (const int*)d_in[3];
  const float* aemb = (const float*)d_in[4];
  const float* bemb = (const float*)d_in[5];
  const float* Wsp = (const float*)d_in[6];
  const float* bsp = (const float*)d_in[7];
  const float* roots = (const float*)d_in[8];
  const float* gamma = (const float*)d_in[9];
  const float* beta = (const float*)d_in[10];
  const float* oW = (const float*)d_in[11];
  const float* ob = (const float*)d_in[12];
  float* out = (float*)d_out;

  // workspace layout (~111.5 MB):
  half_t* AGG = (half_t*)d_ws;                     // [NN*DIM] fp16
  half_t* HB = AGG + (size_t)NN * DIM;             // [NN*DIM] fp16
  float* deg = (float*)(HB + (size_t)NN * DIM);    // [NN]
  float* dinv = deg + NN;                          // [NN]
  float* invdeg = dinv + NN;                       // [NN]
  int* indeg = (int*)(invdeg + NN);                // [NN]
  int* writecur = indeg + NN;                      // [NN]
  uint2* epk2 = (uint2*)(writecur + NN);           // [NE] 8B each
  int* bsum = (int*)(epk2 + NE);                   // [NBLK]
  int* boff = bsum + NBLK;                         // [NBLK]
  half_t* Wfh = (half_t*)(boff + NBLK);            // [5*16384]
  half_t* Wfl = Wfh + 5 * 16384;                   // [5*16384]
  // pooled/cnt overlay dead HB at pool time:
  float* pooled = (float*)HB;                      // [NG*DIM]
  float* cnt = pooled + (size_t)NG * DIM;          // [NG]

  k_init<<<(NN + 255) / 256, 256, 0, stream>>>(deg, indeg);
  k_deg<<<(NE + 255) / 256, 256, 0, stream>>>(ei, deg, indeg);
  k_dinv<<<(NN + 255) / 256, 256, 0, stream>>>(deg, dinv, invdeg);
  k_scansum<<<NBLK, 256, 0, stream>>>(indeg, bsum);
  k_scanmid<<<1, 1024, 0, stream>>>(bsum, boff);
  k_scanfinal<<<NBLK, 256, 0, stream>>>(indeg, boff, writecur);
  k_fill<<<(NE + 255) / 256, 256, 0, stream>>>(ei, ea, dinv, writecur, epk2);
  k_wsplit<<<5 * 16384 / 256, 256, 0, stream>>>(Wsp, Wfh, Wfl);
  k_atom<<<NN / 8, 256, 0, stream>>>(xf, aemb, AGG);

  const int gblocks = (NN + DIM - 1) / DIM;  // 1563
  for (int i = 0; i < 5; ++i) {
    const float* bias = bsp + (size_t)i * DIM;
    const float* root = roots + (size_t)i * DIM;
    k_gemm<<<gblocks, 256, 0, stream>>>(AGG, Wfh + (size_t)i * 16384,
                                        Wfl + (size_t)i * 16384, bias, HB);
    if (i < 4)
      k_gather<1><<<NN / 8, 256, 0, stream>>>(
          indeg, writecur, epk2, bemb + (size_t)i * 3 * BV * DIM, invdeg, root,
          gamma + (size_t)i * DIM, beta + (size_t)i * DIM, HB, AGG);
    else
      k_gather<0><<<NN / 8, 256, 0, stream>>>(
          indeg, writecur, epk2, bemb + (size_t)i * 3 * BV * DIM, invdeg, root,
          nullptr, nullptr, HB, AGG);
  }
  (void)hipMemsetAsync(pooled, 0, (size_t)(NG * DIM + NG) * sizeof(float), stream);
  k_pool<<<NN / 16, 128, 0, stream>>>(AGG, batch, pooled, cnt);
  k_outgemm<<<NG / DIM, 256, 0, stream>>>(pooled, oW, ob, cnt, out);
}

// Round 15
// 689.635 us; speedup vs baseline: 3.0866x; 1.1903x over previous
//
#include <hip/hip_runtime.h>
#include <hip/hip_fp16.h>

#define NN 200000   // nodes
#define NE 600000   // edges
#define NG 8192     // graphs
#define DIM 128
#define AV 119      // atom vocab
#define BV 5        // bond vocab
#define NBLK 782    // ceil(NN/256) for scan

typedef __half half_t;
typedef _Float16 f16x8 __attribute__((ext_vector_type(8)));
typedef float f32x4 __attribute__((ext_vector_type(4)));

union AF { uint4 u; __half2 h[4]; f16x8 v; _Float16 f[8]; };
union H2 { uint2 u; __half2 h[2]; _Float16 f[4]; };

__device__ inline uint2 pack4h(float a, float b, float c, float d) {
  union { uint2 u; __half2 h[2]; } r;
  r.h[0] = __floats2half2_rn(a, b);
  r.h[1] = __floats2half2_rn(c, d);
  return r.u;
}

// ---------------- init ----------------
__global__ __launch_bounds__(256) void k_init(float* __restrict__ deg,
                                              int* __restrict__ indeg) {
  int i = blockIdx.x * 256 + threadIdx.x;
  if (i < NN) { deg[i] = 1.0f; indeg[i] = 0; }
}

// ---------------- degree (over row) + in-degree (over col) ----------------
__global__ __launch_bounds__(256) void k_deg(const int* __restrict__ ei,
                                             float* __restrict__ deg,
                                             int* __restrict__ indeg) {
  int e = blockIdx.x * 256 + threadIdx.x;
  if (e < NE) {
    unsafeAtomicAdd(&deg[ei[e]], 1.0f);
    atomicAdd(&indeg[ei[NE + e]], 1);
  }
}

__global__ __launch_bounds__(256) void k_dinv(const float* __restrict__ deg,
                                              float* __restrict__ dinv,
                                              float* __restrict__ invdeg) {
  int n = blockIdx.x * 256 + threadIdx.x;
  if (n < NN) {
    float d = deg[n];
    dinv[n] = 1.0f / sqrtf(d);
    invdeg[n] = 1.0f / d;
  }
}

// ---------------- 3-phase exclusive scan of indeg -> writecur ----------------
__global__ __launch_bounds__(256) void k_scansum(const int* __restrict__ indeg,
                                                 int* __restrict__ bsum) {
  __shared__ int s[256];
  int i = blockIdx.x * 256 + threadIdx.x;
  int v = (i < NN) ? indeg[i] : 0;
  s[threadIdx.x] = v;
  __syncthreads();
  for (int off = 128; off > 0; off >>= 1) {
    if (threadIdx.x < off) s[threadIdx.x] += s[threadIdx.x + off];
    __syncthreads();
  }
  if (threadIdx.x == 0) bsum[blockIdx.x] = s[0];
}

__global__ __launch_bounds__(1024) void k_scanmid(const int* __restrict__ bsum,
                                                  int* __restrict__ boff) {
  __shared__ int s[1024];
  int t = threadIdx.x;
  int v = (t < NBLK) ? bsum[t] : 0;
  s[t] = v;
  __syncthreads();
  for (int off = 1; off < 1024; off <<= 1) {
    int x = (t >= off) ? s[t - off] : 0;
    __syncthreads();
    s[t] += x;
    __syncthreads();
  }
  if (t < NBLK) boff[t] = s[t] - v;
}

__global__ __launch_bounds__(256) void k_scanfinal(const int* __restrict__ indeg,
                                                   const int* __restrict__ boff,
                                                   int* __restrict__ writecur) {
  __shared__ int s[256];
  int i = blockIdx.x * 256 + threadIdx.x;
  int v = (i < NN) ? indeg[i] : 0;
  s[threadIdx.x] = v;
  __syncthreads();
  for (int off = 1; off < 256; off <<= 1) {
    int x = (threadIdx.x >= off) ? s[threadIdx.x - off] : 0;
    __syncthreads();
    s[threadIdx.x] += x;
    __syncthreads();
  }
  if (i < NN) writecur[i] = s[threadIdx.x] - v + boff[blockIdx.x];
}

// ---------------- fill CSR: epk2[pos] = {row | cidx<<18, norm} ----------------
__global__ __launch_bounds__(256) void k_fill(const int* __restrict__ ei,
                                              const int* __restrict__ ea,
                                              const float* __restrict__ dinv,
                                              int* __restrict__ writecur,
                                              uint2* __restrict__ epk2) {
  int e = blockIdx.x * 256 + threadIdx.x;
  if (e >= NE) return;
  int row = ei[e];
  int col = ei[NE + e];
  int pos = atomicAdd(&writecur[col], 1);
  float nr = dinv[row] * dinv[col];
  uint cidx = (uint)(ea[e * 3] * 25 + ea[e * 3 + 1] * 5 + ea[e * 3 + 2]);
  uint pk = (uint)row | (cidx << 18);
  epk2[pos] = make_uint2(pk, __float_as_uint(nr));
}

// ---------------- combined bond table: bt[l][cidx][d], cidx = a0*25+a1*5+a2 ----------------
__global__ __launch_bounds__(256) void k_bond(const float* __restrict__ bemb,
                                              half_t* __restrict__ bt) {
  int gid = blockIdx.x * 256 + threadIdx.x;  // 5*125*128 = 80000
  if (gid >= 5 * 125 * DIM) return;
  int l = gid / (125 * DIM);
  int r = gid % (125 * DIM);
  int cidx = r / DIM, d = r % DIM;
  int a0 = cidx / 25, a1 = (cidx / 5) % 5, a2 = cidx % 5;
  const float* base = bemb + (size_t)l * 3 * BV * DIM;
  float v = base[(0 * BV + a0) * DIM + d] + base[(1 * BV + a1) * DIM + d] +
            base[(2 * BV + a2) * DIM + d];
  bt[gid] = __float2half(v);
}

// ---------------- AtomEncoder: 32 threads/node, float4 gathers ----------------
__global__ __launch_bounds__(256) void k_atom(const int* __restrict__ xf,
                                              const float* __restrict__ aemb,
                                              half_t* __restrict__ A) {
  int n = blockIdx.x * 8 + (threadIdx.x >> 5);
  int d = (threadIdx.x & 31) * 4;
  float s0 = 0.f, s1 = 0.f, s2 = 0.f, s3 = 0.f;
#pragma unroll
  for (int c = 0; c < 9; ++c) {
    int idx = xf[n * 9 + c];
    float4 v = *(const float4*)(aemb + (size_t)(c * AV + idx) * DIM + d);
    s0 += v.x; s1 += v.y; s2 += v.z; s3 += v.w;
  }
  *(uint2*)(A + (size_t)n * DIM + d) = pack4h(s0, s1, s2, s3);
}

// ---------------- W fp16 split into swapped-operand MFMA fragment order ----------------
// element (k,col): ks=k>>5, kg=(k>>3)&3, j=k&7, mt=col>>4, lr=col&15
//   -> fi = (ks*8+mt)*512 + kg*128 + lr*8 + j
__global__ __launch_bounds__(256) void k_wsplit(const float* __restrict__ Wsp,
                                                half_t* __restrict__ Wfh) {
  int gid = blockIdx.x * 256 + threadIdx.x;  // 5*16384 total
  int l = gid >> 14;
  int r = gid & 16383;
  int k = r >> 7, col = r & 127;
  float w = Wsp[gid];
  int ks = k >> 5, kg = (k >> 3) & 3, j = k & 7;
  int mt = col >> 4, lr = col & 15;
  int fi = (l << 14) | ((ks * 8 + mt) * 512 + kg * 128 + lr * 8 + j);
  *(_Float16*)&Wfh[fi] = (_Float16)w;
}

// ---------------- MFMA layer GEMM: HB = AGG @ W + bias (swapped operands, fp16 W) ----------------
__global__ __launch_bounds__(256) void k_gemm(
    const half_t* __restrict__ Ain, const half_t* __restrict__ Wfh,
    const float* __restrict__ bias, half_t* __restrict__ HB) {
  const int tid = threadIdx.x;
  const int lane = tid & 63;
  const int wave = tid >> 6;
  const int lr = lane & 15;
  const int kg = lane >> 4;
  const int n0 = blockIdx.x * DIM + wave * 32;

  f32x4 acc[8][2];
#pragma unroll
  for (int mt = 0; mt < 8; ++mt)
#pragma unroll
    for (int nt = 0; nt < 2; ++nt) acc[mt][nt] = (f32x4){0.f, 0.f, 0.f, 0.f};

#pragma unroll
  for (int ks = 0; ks < 4; ++ks) {
    const int kb = ks * 32 + kg * 8;
    AF b[2];
#pragma unroll
    for (int nt = 0; nt < 2; ++nt) {
      const int row = n0 + nt * 16 + lr;
      if (row < NN)
        b[nt].u = *(const uint4*)(Ain + (size_t)row * DIM + kb);
      else
        b[nt].u = make_uint4(0u, 0u, 0u, 0u);
    }
#pragma unroll
    for (int mt = 0; mt < 8; ++mt) {
      const int fi = (ks * 8 + mt) * 512 + kg * 128 + lr * 8;
      f16x8 wh = *(const f16x8*)(Wfh + fi);
#pragma unroll
      for (int nt = 0; nt < 2; ++nt) {
        acc[mt][nt] = __builtin_amdgcn_mfma_f32_16x16x32_f16(
            wh, b[nt].v, acc[mt][nt], 0, 0, 0);
      }
    }
  }

  // epilogue: lane holds node = n0+nt*16+lr, features mt*16+kg*4+{0..3}
#pragma unroll
  for (int mt = 0; mt < 8; ++mt) {
    const int f0 = mt * 16 + kg * 4;
    float4 bv = *(const float4*)(bias + f0);
#pragma unroll
    for (int nt = 0; nt < 2; ++nt) {
      const int node = n0 + nt * 16 + lr;
      if (node < NN)
        *(uint2*)(HB + (size_t)node * DIM + f0) =
            pack4h(acc[mt][nt][0] + bv.x, acc[mt][nt][1] + bv.y,
                   acc[mt][nt][2] + bv.z, acc[mt][nt][3] + bv.w);
    }
  }
}

// ---------------- gather: 8-edge chunks, MLP=8, combined bond table ----------------
// AGG[n] = act( relu(HB[n]+root)*invdeg[n] + sum_e norm_e * relu16(HB[row_e]+bt[cidx_e]) )
template <int ACT>
__global__ __launch_bounds__(256) void k_gather(
    const int* __restrict__ indeg, const int* __restrict__ wend,
    const uint2* __restrict__ epk2, const half_t* __restrict__ bt,
    const float* __restrict__ invdeg, const float* __restrict__ root,
    const float* __restrict__ gamma, const float* __restrict__ beta,
    const half_t* __restrict__ HB, half_t* __restrict__ AGG) {
  const int lane = threadIdx.x & 63;
  const int n = blockIdx.x * 8 + (threadIdx.x >> 5);
  const int d = (threadIdx.x & 31) * 4;
  const int t8 = lane & 7;
  const int sbase = lane & 32;

  // self-term (fp32)
  H2 hu; hu.u = *(const uint2*)(HB + (size_t)n * DIM + d);
  float2 slo = __half22float2(hu.h[0]);
  float2 shi = __half22float2(hu.h[1]);
  float4 rt = *(const float4*)(root + d);
  const float idg = invdeg[n];
  float a0 = fmaxf(slo.x + rt.x, 0.f) * idg;
  float a1 = fmaxf(slo.y + rt.y, 0.f) * idg;
  float a2 = fmaxf(shi.x + rt.z, 0.f) * idg;
  float a3 = fmaxf(shi.y + rt.w, 0.f) * idg;

  int cnt = indeg[n];
  int base = wend[n] - cnt;
  while (cnt > 0) {
    const int m = min(cnt, 8);
    uint2 ev = make_uint2(0u, 0u);
    if (t8 < m) ev = epk2[base + t8];
    int pkx[8]; float nrx[8]; uint2 hx[8], ex[8];
#pragma unroll
    for (int t = 0; t < 8; ++t) {
      pkx[t] = __shfl((int)ev.x, sbase | t, 64);
      nrx[t] = __uint_as_float(__shfl((int)ev.y, sbase | t, 64));
      if (t < m) {
        hx[t] = *(const uint2*)(HB + (size_t)(pkx[t] & 0x3FFFF) * DIM + d);
        ex[t] = *(const uint2*)(bt + (size_t)((pkx[t] >> 18) & 127) * DIM + d);
      }
    }
#pragma unroll
    for (int t = 0; t < 8; ++t) {
      if (t < m) {
        H2 hh; hh.u = hx[t];
        H2 ee; ee.u = ex[t];
        float s[4];
#pragma unroll
        for (int q = 0; q < 4; ++q) {
          _Float16 v = (_Float16)(hh.f[q] + ee.f[q]);
          v = (v > (_Float16)0) ? v : (_Float16)0;
          s[q] = (float)v;
        }
        float nr = nrx[t];
        a0 = fmaf(s[0], nr, a0);
        a1 = fmaf(s[1], nr, a1);
        a2 = fmaf(s[2], nr, a2);
        a3 = fmaf(s[3], nr, a3);
      }
    }
    base += 8;
    cnt -= 8;
  }
  if (ACT) {
    const float bns = rsqrtf(1.0f + 1e-5f);
    float4 g = *(const float4*)(gamma + d);
    float4 be = *(const float4*)(beta + d);
    a0 = fmaxf(fmaf(a0, g.x * bns, be.x), 0.f);
    a1 = fmaxf(fmaf(a1, g.y * bns, be.y), 0.f);
    a2 = fmaxf(fmaf(a2, g.z * bns, be.z), 0.f);
    a3 = fmaxf(fmaf(a3, g.w * bns, be.w), 0.f);
  }
  *(uint2*)(AGG + (size_t)n * DIM + d) = pack4h(a0, a1, a2, a3);
}

// ---------------- pooling ----------------
__global__ __launch_bounds__(128) void k_pool(const half_t* __restrict__ A,
                                              const int* __restrict__ batch,
                                              float* __restrict__ pooled,
                                              float* __restrict__ cnt) {
  const int d = threadIdx.x;
  const int base = blockIdx.x * 16;
  int curb = batch[base];
  float acc = 0.f, cacc = 0.f;
#pragma unroll
  for (int i = 0; i < 16; ++i) {
    int n = base + i;
    int b = batch[n];
    if (b != curb) {
      unsafeAtomicAdd(&pooled[(size_t)curb * DIM + d], acc);
      if (d == 0) unsafeAtomicAdd(&cnt[curb], cacc);
      curb = b; acc = 0.f; cacc = 0.f;
    }
    acc += __half2float(A[(size_t)n * DIM + d]);
    cacc += 1.f;
  }
  unsafeAtomicAdd(&pooled[(size_t)curb * DIM + d], acc);
  if (d == 0) unsafeAtomicAdd(&cnt[curb], cacc);
}

// ---------------- output GEMM ----------------
__global__ __launch_bounds__(256) void k_outgemm(const float* __restrict__ P,
                                                 const float* __restrict__ W,
                                                 const float* __restrict__ ob,
                                                 const float* __restrict__ cnt,
                                                 float* __restrict__ out) {
  __shared__ __align__(16) float As[DIM][DIM];
  __shared__ __align__(16) float Wl[DIM][DIM];
  const int tid = threadIdx.x;
  const int bm = blockIdx.x * DIM;
#pragma unroll
  for (int it = 0; it < 16; ++it) {
    int idx = it * 256 + tid;
    ((float4*)&Wl[0][0])[idx] = ((const float4*)W)[idx];
  }
  {
    const int sr = tid >> 1;
    const int sc0 = (tid & 1) * 64;
    const int gr = bm + sr;
#pragma unroll
    for (int j = 0; j < 16; ++j) {
      int c = sc0 + j * 4;
      float4 v = *(const float4*)(P + (size_t)gr * DIM + c);
      As[c + 0][sr] = v.x;
      As[c + 1][sr] = v.y;
      As[c + 2][sr] = v.z;
      As[c + 3][sr] = v.w;
    }
  }
  __syncthreads();
  const int tr = tid >> 4;
  const int tc = tid & 15;
  float acc[8][8];
#pragma unroll
  for (int i = 0; i < 8; ++i)
#pragma unroll
    for (int j = 0; j < 8; ++j) acc[i][j] = 0.f;
#pragma unroll 4
  for (int k = 0; k < DIM; ++k) {
    float a[8], w[8];
    *(float4*)&a[0] = *(const float4*)&As[k][tr * 8];
    *(float4*)&a[4] = *(const float4*)&As[k][tr * 8 + 4];
    *(float4*)&w[0] = *(const float4*)&Wl[k][tc * 4];
    *(float4*)&w[4] = *(const float4*)&Wl[k][64 + tc * 4];
#pragma unroll
    for (int i = 0; i < 8; ++i)
#pragma unroll
      for (int j = 0; j < 8; ++j) acc[i][j] = fmaf(a[i], w[j], acc[i][j]);
  }
  float4 b0 = *(const float4*)(ob + tc * 4);
  float4 b1 = *(const float4*)(ob + 64 + tc * 4);
#pragma unroll
  for (int i = 0; i < 8; ++i) {
    int r = bm + tr * 8 + i;  // 8192 rows exact
    float ic = 1.0f / fmaxf(cnt[r], 1.0f);
    float4 o0, o1;
    o0.x = acc[i][0] * ic + b0.x; o0.y = acc[i][1] * ic + b0.y;
    o0.z = acc[i][2] * ic + b0.z; o0.w = acc[i][3] * ic + b0.w;
    o1.x = acc[i][4] * ic + b1.x; o1.y = acc[i][5] * ic + b1.y;
    o1.z = acc[i][6] * ic + b1.z; o1.w = acc[i][7] * ic + b1.w;
    *(float4*)(out + (size_t)r * DIM + tc * 4) = o0;
    *(float4*)(out + (size_t)r * DIM + 64 + tc * 4) = o1;
  }
}

extern "C" void kernel_launch(void* const* d_in, const int* in_sizes, int n_in,
                              void* d_out, int out_size, void* d_ws, size_t ws_size,
                              hipStream_t stream) {
  const int* xf = (const int*)d_in[0];
  const int* ei = (const int*)d_in[1];
  const int* ea = (const int*)d_in[2];
  const int* batch = (const int*)d_in[3];
  const float* aemb = (const float*)d_in[4];
  const float* bemb = (const float*)d_in[5];
  const float* Wsp = (const float*)d_in[6];
  const float* bsp = (const float*)d_in[7];
  const float* roots = (const float*)d_in[8];
  const float* gamma = (const float*)d_in[9];
  const float* beta = (const float*)d_in[10];
  const float* oW = (const float*)d_in[11];
  const float* ob = (const float*)d_in[12];
  float* out = (float*)d_out;

  // workspace layout (~110 MB):
  half_t* AGG = (half_t*)d_ws;                     // [NN*DIM] fp16
  half_t* HB = AGG + (size_t)NN * DIM;             // [NN*DIM] fp16
  float* deg = (float*)(HB + (size_t)NN * DIM);    // [NN]
  float* dinv = deg + NN;                          // [NN]
  float* invdeg = dinv + NN;                       // [NN]
  int* indeg = (int*)(invdeg + NN);                // [NN]
  int* writecur = indeg + NN;                      // [NN]
  uint2* epk2 = (uint2*)(writecur + NN);           // [NE] 8B each
  int* bsum = (int*)(epk2 + NE);                   // [NBLK]
  int* boff = bsum + NBLK;                         // [NBLK]
  half_t* Wfh = (half_t*)(boff + NBLK);            // [5*16384]
  half_t* bt = Wfh + 5 * 16384;                    // [5*125*128]
  // pooled/cnt overlay dead HB at pool time:
  float* pooled = (float*)HB;                      // [NG*DIM]
  float* cnt = pooled + (size_t)NG * DIM;          // [NG]

  k_init<<<(NN + 255) / 256, 256, 0, stream>>>(deg, indeg);
  k_deg<<<(NE + 255) / 256, 256, 0, stream>>>(ei, deg, indeg);
  k_dinv<<<(NN + 255) / 256, 256, 0, stream>>>(deg, dinv, invdeg);
  k_scansum<<<NBLK, 256, 0, stream>>>(indeg, bsum);
  k_scanmid<<<1, 1024, 0, stream>>>(bsum, boff);
  k_scanfinal<<<NBLK, 256, 0, stream>>>(indeg, boff, writecur);
  k_fill<<<(NE + 255) / 256, 256, 0, stream>>>(ei, ea, dinv, writecur, epk2);
  k_wsplit<<<5 * 16384 / 256, 256, 0, stream>>>(Wsp, Wfh);
  k_bond<<<(5 * 125 * DIM + 255) / 256, 256, 0, stream>>>(bemb, bt);
  k_atom<<<NN / 8, 256, 0, stream>>>(xf, aemb, AGG);

  const int gblocks = (NN + DIM - 1) / DIM;  // 1563
  for (int i = 0; i < 5; ++i) {
    const float* bias = bsp + (size_t)i * DIM;
    const float* root = roots + (size_t)i * DIM;
    k_gemm<<<gblocks, 256, 0, stream>>>(AGG, Wfh + (size_t)i * 16384, bias, HB);
    if (i < 4)
      k_gather<1><<<NN / 8, 256, 0, stream>>>(
          indeg, writecur, epk2, bt + (size_t)i * 125 * DIM, invdeg, root,
          gamma + (size_t)i * DIM, beta + (size_t)i * DIM, HB, AGG);
    else
      k_gather<0><<<NN / 8, 256, 0, stream>>>(
          indeg, writecur, epk2, bt + (size_t)i * 125 * DIM, invdeg, root,
          nullptr, nullptr, HB, AGG);
  }
  (void)hipMemsetAsync(pooled, 0, (size_t)(NG * DIM + NG) * sizeof(float), stream);
  k_pool<<<NN / 16, 128, 0, stream>>>(AGG, batch, pooled, cnt);
  k_outgemm<<<NG / DIM, 256, 0, stream>>>(pooled, oW, ob, cnt, out);
}